// Round 4
// baseline (2600.319 us; speedup 1.0000x reference)
//
#include <hip/hip_runtime.h>
#include <math.h>

#define NB      256
#define LL      128
#define NN      32768
#define DLLM    1024
#define COH     64
#define DD      256
#define NHEAD   4
#define DHD     64
#define NLAYERS 4
#define EDIM    64
#define NETT    8
#define NE      131072

typedef unsigned short bf16_t;

__device__ __forceinline__ float bf2f(bf16_t u){
    return __uint_as_float(((unsigned int)u) << 16);
}
__device__ __forceinline__ bf16_t f2bf(float f){
    unsigned int x = __float_as_uint(f);
    return (bf16_t)((x + 0x7fffu + ((x >> 16) & 1u)) >> 16);
}

__device__ __forceinline__ float gelu_exact(float x){
    return 0.5f * x * (1.0f + erff(x * 0.70710678118654752440f));
}

__device__ __forceinline__ float wave_reduce_sum(float v){
#pragma unroll
    for (int off = 32; off; off >>= 1) v += __shfl_xor(v, off);
    return v;
}

__global__ void zero_kernel(int* __restrict__ p, int n){
    int i = blockIdx.x * blockDim.x + threadIdx.x;
    if (i < n) p[i] = 0;
}

// ---- per-row LayerNorm stats of atom_llm (rows of 1024) ----
__global__ __launch_bounds__(256)
void rowstats_kernel(const float* __restrict__ A, float* __restrict__ stats){
    int wave = threadIdx.x >> 6, lane = threadIdx.x & 63;
    int row = (blockIdx.x << 2) + wave;
    const float* p = A + (size_t)row * DLLM;
    float s = 0.f, sq = 0.f;
#pragma unroll
    for (int c = 0; c < 4; c++){
        float4 v = *(const float4*)(p + c * 256 + (lane << 2));
        s  += v.x + v.y + v.z + v.w;
        sq += v.x*v.x + v.y*v.y + v.z*v.z + v.w*v.w;
    }
    s = wave_reduce_sum(s); sq = wave_reduce_sum(sq);
    float mean = s * (1.0f / DLLM);
    float var  = sq * (1.0f / DLLM) - mean * mean;
    float rstd = rsqrtf(var + 1e-5f);
    if (lane == 0){ stats[row*2] = mean; stats[row*2+1] = rstd; }
}

// ---- precompute eproj[l][t][:] = LN(edge_emb[t]) @ We[l]  (only 8 types) ----
__global__ __launch_bounds__(256)
void edgeproj_kernel(const float* __restrict__ edge_emb,
                     const float* __restrict__ lg, const float* __restrict__ lb,
                     const float* __restrict__ We, float* __restrict__ eproj){
    int l = blockIdx.x >> 3, t = blockIdx.x & 7;
    __shared__ float ea[EDIM];
    int tid = threadIdx.x;
    if (tid < 64){
        float v = edge_emb[t * EDIM + tid];
        float s = v, sq = v * v;
#pragma unroll
        for (int off = 32; off; off >>= 1){ s += __shfl_xor(s, off); sq += __shfl_xor(sq, off); }
        float mean = s * (1.f/64.f);
        float var  = sq * (1.f/64.f) - mean * mean;
        float rstd = rsqrtf(var + 1e-5f);
        ea[tid] = (v - mean) * rstd * lg[tid] + lb[tid];
    }
    __syncthreads();
    const float* W = We + (size_t)l * EDIM * DD;
    float s = 0.f;
#pragma unroll
    for (int k = 0; k < EDIM; k++) s += ea[k] * W[k * DD + tid];
    eproj[((l << 3) + t) * DD + tid] = s;
}

// ---- CSR build over dst ----
__global__ void count_kernel(const int* __restrict__ dst, int* __restrict__ cnt){
    int e = blockIdx.x * blockDim.x + threadIdx.x;
    if (e < NE){
        int d = dst[e];
        if (d >= 0 && d < NN) atomicAdd(&cnt[d], 1);
    }
}

__global__ __launch_bounds__(1024)
void scan_kernel(const int* __restrict__ cnt, int* __restrict__ rowstart, int* __restrict__ cursor){
    __shared__ int sh[1024];
    int tid = threadIdx.x;
    int carry = 0;
    for (int base = 0; base < NN; base += 1024){
        int v = cnt[base + tid];
        sh[tid] = v; __syncthreads();
        for (int off = 1; off < 1024; off <<= 1){
            int t = (tid >= off) ? sh[tid - off] : 0;
            __syncthreads();
            sh[tid] += t;
            __syncthreads();
        }
        int excl = carry + sh[tid] - v;
        rowstart[base + tid] = excl;
        cursor[base + tid]   = excl;
        carry += sh[1023];
        __syncthreads();
    }
    if (tid == 0) rowstart[NN] = carry;
}

__global__ void scatter_kernel(const int* __restrict__ dst, int* __restrict__ cursor,
                               int* __restrict__ eidx){
    int e = blockIdx.x * blockDim.x + threadIdx.x;
    if (e < NE){
        int d = dst[e];
        if (d >= 0 && d < NN){
            int p = atomicAdd(&cursor[d], 1);
            if (p >= 0 && p < NE) eidx[p] = e;
        }
    }
}

// ---- generic tiled GEMM (fp32 math): C = [epi](A @ B [+bias] [+C]) ----
// 64x64 tile, 256 threads, 4x4 per thread. A/C may be bf16-stored.
template<bool A_BF16, bool C_BF16, bool LN_A, bool HAS_BIAS, bool ACC, bool GELU_EP, bool ROWSCALE>
__global__ __launch_bounds__(256)
void gemm_kernel(const void* __restrict__ Av, const float* __restrict__ Bw,
                 void* __restrict__ Cv, int M, int Ncols, int K,
                 const float* __restrict__ bias,
                 const float* __restrict__ stats,
                 const float* __restrict__ lng, const float* __restrict__ lnb,
                 const float* __restrict__ rowscale)
{
    __shared__ __align__(16) float As[16][68];
    __shared__ __align__(16) float Bs[16][64];
    const int tid = threadIdx.x;
    const int tx = tid & 15, ty = tid >> 4;
    const int rowBase = blockIdx.y << 6;
    const int colBase = blockIdx.x << 6;
    const int arow = tid >> 2, akoff = (tid & 3) << 2;
    const int brow = tid >> 4, bcol = (tid & 15) << 2;

    float mean = 0.f, rstd = 0.f;
    if constexpr (LN_A){
        mean = stats[(rowBase + arow) * 2];
        rstd = stats[(rowBase + arow) * 2 + 1];
    }
    const float*  Aptr32 = (const float*)Av  + (size_t)(rowBase + arow) * K + akoff;
    const bf16_t* Aptr16 = (const bf16_t*)Av + (size_t)(rowBase + arow) * K + akoff;
    const float* Bptr = Bw + (size_t)brow * Ncols + colBase + bcol;

    float acc[4][4] = {{0.f}};
    for (int k0 = 0; k0 < K; k0 += 16){
        float4 av;
        if constexpr (A_BF16){
            ushort4 u = *(const ushort4*)(Aptr16 + k0);
            av.x = bf2f(u.x); av.y = bf2f(u.y); av.z = bf2f(u.z); av.w = bf2f(u.w);
        } else {
            av = *(const float4*)(Aptr32 + k0);
        }
        if constexpr (LN_A){
            float4 g4 = *(const float4*)(lng + k0 + akoff);
            float4 b4 = *(const float4*)(lnb + k0 + akoff);
            av.x = (av.x - mean) * rstd * g4.x + b4.x;
            av.y = (av.y - mean) * rstd * g4.y + b4.y;
            av.z = (av.z - mean) * rstd * g4.z + b4.z;
            av.w = (av.w - mean) * rstd * g4.w + b4.w;
        }
        As[akoff+0][arow] = av.x; As[akoff+1][arow] = av.y;
        As[akoff+2][arow] = av.z; As[akoff+3][arow] = av.w;
        float4 bv = *(const float4*)(Bptr + (size_t)k0 * Ncols);
        *(float4*)&Bs[brow][bcol] = bv;
        __syncthreads();
#pragma unroll
        for (int k = 0; k < 16; k++){
            const float4 a4 = *(const float4*)&As[k][ty << 2];
            const float4 b4 = *(const float4*)&Bs[k][tx << 2];
            const float ar[4] = {a4.x, a4.y, a4.z, a4.w};
            const float br[4] = {b4.x, b4.y, b4.z, b4.w};
#pragma unroll
            for (int i = 0; i < 4; i++)
#pragma unroll
                for (int j = 0; j < 4; j++)
                    acc[i][j] = fmaf(ar[i], br[j], acc[i][j]);
        }
        __syncthreads();
    }

#pragma unroll
    for (int i = 0; i < 4; i++){
        int row = rowBase + (ty << 2) + i;
        int col = colBase + (tx << 2);
        float4 r = make_float4(acc[i][0], acc[i][1], acc[i][2], acc[i][3]);
        if constexpr (HAS_BIAS){
            float4 b4 = *(const float4*)(bias + col);
            r.x += b4.x; r.y += b4.y; r.z += b4.z; r.w += b4.w;
        }
        if constexpr (ACC){
            const float4 c4 = *(const float4*)((const float*)Cv + (size_t)row * Ncols + col);
            r.x += c4.x; r.y += c4.y; r.z += c4.z; r.w += c4.w;
        }
        if constexpr (GELU_EP){
            r.x = gelu_exact(r.x); r.y = gelu_exact(r.y);
            r.z = gelu_exact(r.z); r.w = gelu_exact(r.w);
        }
        if constexpr (ROWSCALE){
            float s = rowscale[row];
            r.x *= s; r.y *= s; r.z *= s; r.w *= s;
        }
        if constexpr (C_BF16){
            ushort4 u;
            u.x = f2bf(r.x); u.y = f2bf(r.y); u.z = f2bf(r.z); u.w = f2bf(r.w);
            *(ushort4*)((bf16_t*)Cv + (size_t)row * Ncols + col) = u;
        } else {
            *(float4*)((float*)Cv + (size_t)row * Ncols + col) = r;
        }
    }
}

// ---- per-dst-node attention (bf16 q/k/v, fp32 math): one block/node, one wave/head ----
__global__ __launch_bounds__(256)
void attn_kernel(const bf16_t* __restrict__ Q, const bf16_t* __restrict__ Kf,
                 const bf16_t* __restrict__ Vf,
                 const int* __restrict__ rowstart, const int* __restrict__ eidx,
                 const int* __restrict__ src, const int* __restrict__ etype,
                 const float* __restrict__ eproj, bf16_t* __restrict__ outp)
{
    int node = blockIdx.x;
    int wave = threadIdx.x >> 6, lane = threadIdx.x & 63;
    int fdim = (wave << 6) + lane;
    __shared__ float sh_a[4][256];
    __shared__ int   sh_e[256];
    int s0 = rowstart[node];
    int deg = rowstart[node + 1] - s0;
    if (deg > 256) deg = 256;
    if (deg < 0) deg = 0;
    if (threadIdx.x < deg){
        int e = eidx[s0 + threadIdx.x];
        int sv = src[e]; if (sv < 0 || sv >= NN) sv = 0;
        sh_e[threadIdx.x] = (sv << 3) | (etype[e] & 7);
    }
    __syncthreads();
    float q = bf2f(Q[(size_t)node * DD + fdim]);
    float ep[NETT];
#pragma unroll
    for (int t = 0; t < NETT; t++) ep[t] = eproj[t * DD + fdim];
    float m = -1e30f;
    for (int i = 0; i < deg; i++){
        int pk = sh_e[i];
        int s = pk >> 3, t = pk & 7;
        float kv = bf2f(Kf[(size_t)s * DD + fdim]) + ep[t];
        float d = q * kv;
#pragma unroll
        for (int off = 32; off; off >>= 1) d += __shfl_xor(d, off);
        d *= 0.125f;  // 1/sqrt(64)
        if (lane == 0) sh_a[wave][i] = d;
        m = fmaxf(m, d);
    }
    float den = 0.f;
    for (int i = 0; i < deg; i++){
        float ex = expf(sh_a[wave][i] - m);
        if (lane == 0) sh_a[wave][i] = ex;
        den += ex;
    }
    float invden = (deg > 0) ? 1.f / den : 0.f;
    float acc = 0.f;
    for (int i = 0; i < deg; i++){
        int pk = sh_e[i];
        int s = pk >> 3, t = pk & 7;
        float vv = bf2f(Vf[(size_t)s * DD + fdim]) + ep[t];
        acc += sh_a[wave][i] * invden * vv;
    }
    outp[(size_t)node * DD + fdim] = f2bf(acc);
}

// ---- beta gate + residual: S = h + beta*xr + (1-beta)*out ----
__global__ __launch_bounds__(256)
void beta_combine_kernel(const float* __restrict__ h, const bf16_t* __restrict__ outp,
                         const bf16_t* __restrict__ xr, const float* __restrict__ Wb,
                         float* __restrict__ S)
{
    int wave = threadIdx.x >> 6, lane = threadIdx.x & 63;
    int node = (blockIdx.x << 2) + wave;
    int d0 = lane << 2;
    ushort4 ou = *(const ushort4*)(outp + (size_t)node * DD + d0);
    ushort4 xu = *(const ushort4*)(xr   + (size_t)node * DD + d0);
    float4 o = make_float4(bf2f(ou.x), bf2f(ou.y), bf2f(ou.z), bf2f(ou.w));
    float4 x = make_float4(bf2f(xu.x), bf2f(xu.y), bf2f(xu.z), bf2f(xu.w));
    float4 w0 = *(const float4*)(Wb + d0);
    float4 w1 = *(const float4*)(Wb + 256 + d0);
    float4 w2 = *(const float4*)(Wb + 512 + d0);
    float p = o.x*w0.x + o.y*w0.y + o.z*w0.z + o.w*w0.w
            + x.x*w1.x + x.y*w1.y + x.z*w1.z + x.w*w1.w
            + (o.x-x.x)*w2.x + (o.y-x.y)*w2.y + (o.z-x.z)*w2.z + (o.w-x.w)*w2.w;
    p = wave_reduce_sum(p);
    float beta = 1.f / (1.f + expf(-p));
    float4 hv = *(const float4*)(h + (size_t)node * DD + d0);
    float4 r;
    r.x = hv.x + beta * x.x + (1.f - beta) * o.x;
    r.y = hv.y + beta * x.y + (1.f - beta) * o.y;
    r.z = hv.z + beta * x.z + (1.f - beta) * o.z;
    r.w = hv.w + beta * x.w + (1.f - beta) * o.w;
    *(float4*)(S + (size_t)node * DD + d0) = r;
}

// ---- GraphNorm (per graph, per dim over 128 nodes) + exact GELU ----
__global__ __launch_bounds__(256)
void graphnorm_gelu_kernel(const float* __restrict__ xin, const float* __restrict__ w,
                           const float* __restrict__ b, const float* __restrict__ ms,
                           float* __restrict__ hout)
{
    int g = blockIdx.x, d = threadIdx.x;
    const float* base = xin + (size_t)g * LL * DD + d;
    float s = 0.f;
    for (int n = 0; n < LL; n++) s += base[n * DD];
    float sub = s * (1.f / LL) * ms[d];
    float var = 0.f;
    for (int n = 0; n < LL; n++){ float t = base[n * DD] - sub; var += t * t; }
    var *= (1.f / LL);
    float rs = rsqrtf(var + 1e-5f);
    float wd = w[d], bd = b[d];
    float* ob = hout + (size_t)g * LL * DD + d;
    for (int n = 0; n < LL; n++){
        float t = (base[n * DD] - sub) * rs * wd + bd;
        ob[n * DD] = gelu_exact(t);
    }
}

// ---- final: out = LN(h + ff) * mask  (ff aliases outp; per-thread in-place safe) ----
__global__ __launch_bounds__(256)
void final_ln_kernel(const float* __restrict__ h, const float* __restrict__ ff,
                     const float* __restrict__ g, const float* __restrict__ b,
                     const float* __restrict__ mask, float* __restrict__ outp)
{
    int wave = threadIdx.x >> 6, lane = threadIdx.x & 63;
    int node = (blockIdx.x << 2) + wave;
    int d0 = lane << 2;
    float4 hv = *(const float4*)(h  + (size_t)node * DD + d0);
    float4 fv = *(const float4*)(ff + (size_t)node * DD + d0);
    float4 v; v.x = hv.x + fv.x; v.y = hv.y + fv.y; v.z = hv.z + fv.z; v.w = hv.w + fv.w;
    float s  = v.x + v.y + v.z + v.w;
    float sq = v.x*v.x + v.y*v.y + v.z*v.z + v.w*v.w;
    s = wave_reduce_sum(s); sq = wave_reduce_sum(sq);
    float mean = s * (1.f / DD);
    float var  = sq * (1.f / DD) - mean * mean;
    float rs = rsqrtf(var + 1e-5f);
    float mk = mask[node];
    float4 g4 = *(const float4*)(g + d0), b4 = *(const float4*)(b + d0);
    float4 r;
    r.x = ((v.x - mean) * rs * g4.x + b4.x) * mk;
    r.y = ((v.y - mean) * rs * g4.y + b4.y) * mk;
    r.z = ((v.z - mean) * rs * g4.z + b4.z) * mk;
    r.w = ((v.w - mean) * rs * g4.w + b4.w) * mk;
    *(float4*)(outp + (size_t)node * DD + d0) = r;
}

extern "C" void kernel_launch(void* const* d_in, const int* in_sizes, int n_in,
                              void* d_out, int out_size, void* d_ws, size_t ws_size,
                              hipStream_t stream)
{
    // Sanity guards: bail cleanly (live container, absmax failure) rather than fault.
    if (n_in < 33) return;
    if (in_sizes[0] != NN * DLLM) return;          // atom_llm
    if (in_sizes[3] != 2 * NE) return;             // edge_index
    if (in_sizes[8] != DLLM * DD) return;          // W_llm
    if (in_sizes[27] != DD * 4 * DD) return;       // W1
    if (out_size != NN * DD) return;

    const float* atom_llm    = (const float*)d_in[0];
    const float* atom_onehot = (const float*)d_in[1];
    const float* mask        = (const float*)d_in[2];
    const int*   edge_index  = (const int*)d_in[3];
    const int*   etype       = (const int*)d_in[4];
    const float* ln_llm_g    = (const float*)d_in[6];
    const float* ln_llm_b    = (const float*)d_in[7];
    const float* W_llm       = (const float*)d_in[8];
    const float* b_llm       = (const float*)d_in[9];
    const float* W_oh        = (const float*)d_in[10];
    const float* edge_emb    = (const float*)d_in[11];
    const float* edge_ln_g   = (const float*)d_in[12];
    const float* edge_ln_b   = (const float*)d_in[13];
    const float* Wq          = (const float*)d_in[14];
    const float* bq          = (const float*)d_in[15];
    const float* Wk          = (const float*)d_in[16];
    const float* bk          = (const float*)d_in[17];
    const float* Wv          = (const float*)d_in[18];
    const float* bv          = (const float*)d_in[19];
    const float* We          = (const float*)d_in[20];
    const float* Ws          = (const float*)d_in[21];
    const float* bs          = (const float*)d_in[22];
    const float* Wb          = (const float*)d_in[23];
    const float* gn_w        = (const float*)d_in[24];
    const float* gn_b        = (const float*)d_in[25];
    const float* gn_ms       = (const float*)d_in[26];
    const float* W1          = (const float*)d_in[27];
    const float* b1          = (const float*)d_in[28];
    const float* W2          = (const float*)d_in[29];
    const float* b2          = (const float*)d_in[30];
    const float* out_ln_g    = (const float*)d_in[31];
    const float* out_ln_b    = (const float*)d_in[32];

    const int* srcv = edge_index;
    const int* dstv = edge_index + NE;

    char* ws = (char*)d_ws;
    size_t off = 0;
    auto alloc = [&](size_t bytes) -> char* {
        char* p = ws + off; off += (bytes + 255) / 256 * 256; return p;
    };
    const size_t NODE_F  = (size_t)NN * DD * sizeof(float);   // 33.55 MB
    const size_t NODE_H  = (size_t)NN * DD * sizeof(bf16_t);  // 16.78 MB
    float*  h    = (float*)alloc(NODE_F);
    bf16_t* qb   = (bf16_t*)alloc(NODE_H);  // qb..xrb contiguous, reused as t1 (N x 1024 bf16)
    bf16_t* kb   = (bf16_t*)alloc(NODE_H);
    bf16_t* vb   = (bf16_t*)alloc(NODE_H);
    bf16_t* xrb  = (bf16_t*)alloc(NODE_H);
    bf16_t* ao   = (bf16_t*)alloc(NODE_H);  // attention output (bf16)
    float* eproj = (float*)alloc((size_t)NLAYERS * NETT * DD * sizeof(float));
    float* stats = (float*)alloc((size_t)NN * 2 * sizeof(float));
    int* cnt      = (int*)alloc((size_t)NN * sizeof(int));
    int* rowstart = (int*)alloc((size_t)(NN + 1) * sizeof(int));
    int* cursor   = (int*)alloc((size_t)NN * sizeof(int));
    int* eidx     = (int*)alloc((size_t)NE * sizeof(int));
    bf16_t* t1 = qb;            // N x 1024 bf16 (exactly spans qb..xrb)
    float*  S  = (float*)d_out; // f32 scratch: beta output / gnorm input / FFN t2

    // Fail-safe: workspace too small -> clean bail (absmax failure, live container).
    if (ws_size < off) return;

    // CSR build (zero via kernel, not hipMemsetAsync — zero runtime-API surface in capture)
    zero_kernel<<<NN / 256, 256, 0, stream>>>(cnt, NN);
    count_kernel<<<NE / 256, 256, 0, stream>>>(dstv, cnt);
    scan_kernel<<<1, 1024, 0, stream>>>(cnt, rowstart, cursor);
    scatter_kernel<<<NE / 256, 256, 0, stream>>>(dstv, cursor, eidx);

    // precompute
    rowstats_kernel<<<NN / 4, 256, 0, stream>>>(atom_llm, stats);
    edgeproj_kernel<<<NLAYERS * NETT, 256, 0, stream>>>(edge_emb, edge_ln_g, edge_ln_b, We, eproj);

    // h = onehot @ W_oh ; then h = (LN(atom_llm) @ W_llm + b_llm + h) * mask
    {
        dim3 grid(DD / 64, NN / 64);
        gemm_kernel<false,false,false,false,false,false,false><<<grid, 256, 0, stream>>>(
            atom_onehot, W_oh, h, NN, DD, COH, nullptr, nullptr, nullptr, nullptr, nullptr);
        gemm_kernel<false,false,true,true,true,false,true><<<grid, 256, 0, stream>>>(
            atom_llm, W_llm, h, NN, DD, DLLM, b_llm, stats, ln_llm_g, ln_llm_b, mask);
    }

    for (int l = 0; l < NLAYERS; l++){
        dim3 grid(DD / 64, NN / 64);
        const float* Wql = Wq + (size_t)l * DD * DD;
        const float* Wkl = Wk + (size_t)l * DD * DD;
        const float* Wvl = Wv + (size_t)l * DD * DD;
        const float* Wsl = Ws + (size_t)l * DD * DD;
        gemm_kernel<false,true,false,true,false,false,false><<<grid, 256, 0, stream>>>(
            h, Wql, qb, NN, DD, DD, bq + l * DD, nullptr, nullptr, nullptr, nullptr);
        gemm_kernel<false,true,false,true,false,false,false><<<grid, 256, 0, stream>>>(
            h, Wkl, kb, NN, DD, DD, bk + l * DD, nullptr, nullptr, nullptr, nullptr);
        gemm_kernel<false,true,false,true,false,false,false><<<grid, 256, 0, stream>>>(
            h, Wvl, vb, NN, DD, DD, bv + l * DD, nullptr, nullptr, nullptr, nullptr);
        gemm_kernel<false,true,false,true,false,false,false><<<grid, 256, 0, stream>>>(
            h, Wsl, xrb, NN, DD, DD, bs + l * DD, nullptr, nullptr, nullptr, nullptr);

        attn_kernel<<<NN, 256, 0, stream>>>(qb, kb, vb, rowstart, eidx, srcv, etype,
                                            eproj + (size_t)l * NETT * DD, ao);

        beta_combine_kernel<<<NN / 4, 256, 0, stream>>>(h, ao, xrb, Wb + (size_t)l * 768, S);

        graphnorm_gelu_kernel<<<NB, 256, 0, stream>>>(S, gn_w + l * DD, gn_b + l * DD,
                                                      gn_ms + l * DD, h);
    }

    // FFN: t1 = gelu(h @ W1 + b1) [bf16]; t2 = t1 @ W2 + b2 [->S]; out = LN(h + t2) * mask
    {
        dim3 grid1(4 * DD / 64, NN / 64);
        gemm_kernel<false,true,false,true,false,true,false><<<grid1, 256, 0, stream>>>(
            h, W1, t1, NN, 4 * DD, DD, b1, nullptr, nullptr, nullptr, nullptr);
        dim3 grid2(DD / 64, NN / 64);
        gemm_kernel<true,false,false,true,false,false,false><<<grid2, 256, 0, stream>>>(
            t1, W2, S, NN, DD, 4 * DD, b2, nullptr, nullptr, nullptr, nullptr);
        final_ln_kernel<<<NN / 4, 256, 0, stream>>>(h, S, out_ln_g, out_ln_b, mask,
                                                    (float*)d_out);
    }
}

// Round 5
// 1263.877 us; speedup vs baseline: 2.0574x; 2.0574x over previous
//
#include <hip/hip_runtime.h>
#include <math.h>

#define NB      256
#define LL      128
#define NN      32768
#define DLLM    1024
#define COH     64
#define DD      256
#define NLAYERS 4
#define EDIM    64
#define NETT    8
#define NE      131072

typedef unsigned short bf16_t;
typedef __bf16 bf16x8 __attribute__((ext_vector_type(8)));
typedef float f32x4v __attribute__((ext_vector_type(4)));

__device__ __forceinline__ float bf2f(bf16_t u){
    return __uint_as_float(((unsigned int)u) << 16);
}
__device__ __forceinline__ bf16_t f2bf(float f){
    unsigned int x = __float_as_uint(f);
    return (bf16_t)((x + 0x7fffu + ((x >> 16) & 1u)) >> 16);
}
__device__ __forceinline__ unsigned pack2(float a, float b){
    return (unsigned)f2bf(a) | ((unsigned)f2bf(b) << 16);
}
__device__ __forceinline__ float gelu_exact(float x){
    return 0.5f * x * (1.0f + erff(x * 0.70710678118654752440f));
}
__device__ __forceinline__ float wave_reduce_sum(float v){
#pragma unroll
    for (int off = 32; off; off >>= 1) v += __shfl_xor(v, off);
    return v;
}

__global__ void zero_kernel(int* __restrict__ p, int n){
    int i = blockIdx.x * blockDim.x + threadIdx.x;
    if (i < n) p[i] = 0;
}

// ---- LN(atom_llm)*g+b -> bf16, concat onehot -> xln [NN][1088] ----
__global__ __launch_bounds__(256)
void ln_concat_kernel(const float* __restrict__ A, const float* __restrict__ onehot,
                      const float* __restrict__ g, const float* __restrict__ b,
                      bf16_t* __restrict__ xln){
    int wave = threadIdx.x >> 6, lane = threadIdx.x & 63;
    int row = (blockIdx.x << 2) + wave;
    const float* p = A + (size_t)row * DLLM;
    float4 v[4];
    float s = 0.f, sq = 0.f;
#pragma unroll
    for (int c = 0; c < 4; c++){
        v[c] = *(const float4*)(p + c * 256 + (lane << 2));
        s  += v[c].x + v[c].y + v[c].z + v[c].w;
        sq += v[c].x*v[c].x + v[c].y*v[c].y + v[c].z*v[c].z + v[c].w*v[c].w;
    }
    s = wave_reduce_sum(s); sq = wave_reduce_sum(sq);
    float mean = s * (1.0f / DLLM);
    float var  = sq * (1.0f / DLLM) - mean * mean;
    float rstd = rsqrtf(var + 1e-5f);
    bf16_t* out = xln + (size_t)row * 1088;
#pragma unroll
    for (int c = 0; c < 4; c++){
        float4 g4 = *(const float4*)(g + c * 256 + (lane << 2));
        float4 b4 = *(const float4*)(b + c * 256 + (lane << 2));
        float rx = (v[c].x - mean) * rstd * g4.x + b4.x;
        float ry = (v[c].y - mean) * rstd * g4.y + b4.y;
        float rz = (v[c].z - mean) * rstd * g4.z + b4.z;
        float rw = (v[c].w - mean) * rstd * g4.w + b4.w;
        ushort4 u; u.x = f2bf(rx); u.y = f2bf(ry); u.z = f2bf(rz); u.w = f2bf(rw);
        *(ushort4*)(out + c * 256 + (lane << 2)) = u;
    }
    out[1024 + lane] = f2bf(onehot[(size_t)row * COH + lane]);
}

// ---- eproj[l][t][:] = LN(edge_emb[t]) @ We[l] ----
__global__ __launch_bounds__(256)
void edgeproj_kernel(const float* __restrict__ edge_emb,
                     const float* __restrict__ lg, const float* __restrict__ lb,
                     const float* __restrict__ We, float* __restrict__ eproj){
    int l = blockIdx.x >> 3, t = blockIdx.x & 7;
    __shared__ float ea[EDIM];
    int tid = threadIdx.x;
    if (tid < 64){
        float v = edge_emb[t * EDIM + tid];
        float s = v, sq = v * v;
#pragma unroll
        for (int off = 32; off; off >>= 1){ s += __shfl_xor(s, off); sq += __shfl_xor(sq, off); }
        float mean = s * (1.f/64.f);
        float var  = sq * (1.f/64.f) - mean * mean;
        float rstd = rsqrtf(var + 1e-5f);
        ea[tid] = (v - mean) * rstd * lg[tid] + lb[tid];
    }
    __syncthreads();
    const float* W = We + (size_t)l * EDIM * DD;
    float s = 0.f;
#pragma unroll
    for (int k = 0; k < EDIM; k++) s += ea[k] * W[k * DD + tid];
    eproj[((l << 3) + t) * DD + tid] = s;
}

// ---- CSR build over dst ----
__global__ void count_kernel(const int* __restrict__ dst, int* __restrict__ cnt){
    int e = blockIdx.x * blockDim.x + threadIdx.x;
    if (e < NE){
        int d = dst[e];
        if (d >= 0 && d < NN) atomicAdd(&cnt[d], 1);
    }
}

__global__ __launch_bounds__(1024)
void scan_kernel(const int* __restrict__ cnt, int* __restrict__ rowstart, int* __restrict__ cursor){
    __shared__ int sh[1024];
    int tid = threadIdx.x;
    int carry = 0;
    for (int base = 0; base < NN; base += 1024){
        int v = cnt[base + tid];
        sh[tid] = v; __syncthreads();
        for (int off = 1; off < 1024; off <<= 1){
            int t = (tid >= off) ? sh[tid - off] : 0;
            __syncthreads();
            sh[tid] += t;
            __syncthreads();
        }
        int excl = carry + sh[tid] - v;
        rowstart[base + tid] = excl;
        cursor[base + tid]   = excl;
        carry += sh[1023];
        __syncthreads();
    }
    if (tid == 0) rowstart[NN] = carry;
}

__global__ void scatter_kernel(const int* __restrict__ dst, int* __restrict__ cursor,
                               int* __restrict__ eidx){
    int e = blockIdx.x * blockDim.x + threadIdx.x;
    if (e < NE){
        int d = dst[e];
        if (d >= 0 && d < NN){
            int p = atomicAdd(&cursor[d], 1);
            if (p >= 0 && p < NE) eidx[p] = e;
        }
    }
}

// ---- weight conversion / transposition to bf16 ----
__global__ void wcvt_in_kernel(const float* __restrict__ Wllm, const float* __restrict__ Woh,
                               bf16_t* __restrict__ dst){   // [256][1088]
    int idx = blockIdx.x * blockDim.x + threadIdx.x;
    if (idx >= 256 * 1088) return;
    int n = idx / 1088, k = idx % 1088;
    float v = (k < 1024) ? Wllm[(size_t)k * 256 + n] : Woh[(size_t)(k - 1024) * 256 + n];
    dst[idx] = f2bf(v);
}

__global__ void wcvt_qkvs_kernel(const float* __restrict__ Wq, const float* __restrict__ Wk,
                                 const float* __restrict__ Wv, const float* __restrict__ Ws,
                                 bf16_t* __restrict__ dst){  // [L][1024][256]
    int idx = blockIdx.x * blockDim.x + threadIdx.x;
    if (idx >= NLAYERS * 1024 * 256) return;
    int l = idx >> 18, rem = idx & 262143;
    int n = rem >> 8, k = rem & 255;
    int sel = n >> 8, nn = n & 255;
    const float* W = (sel == 0) ? Wq : (sel == 1) ? Wk : (sel == 2) ? Wv : Ws;
    dst[idx] = f2bf(W[(size_t)l * 65536 + (size_t)k * 256 + nn]);
}

__global__ void wcvt_w1_kernel(const float* __restrict__ W1, bf16_t* __restrict__ dst){ // [1024][256]
    int idx = blockIdx.x * blockDim.x + threadIdx.x;
    if (idx >= 1024 * 256) return;
    int n = idx >> 8, k = idx & 255;
    dst[idx] = f2bf(W1[(size_t)k * 1024 + n]);
}

__global__ void wcvt_w2_kernel(const float* __restrict__ W2, bf16_t* __restrict__ dst){ // [256][1024]
    int idx = blockIdx.x * blockDim.x + threadIdx.x;
    if (idx >= 256 * 1024) return;
    int n = idx >> 10, k = idx & 1023;
    dst[idx] = f2bf(W2[(size_t)k * 256 + n]);
}

__global__ void pack_bias_kernel(const float* __restrict__ bq, const float* __restrict__ bk,
                                 const float* __restrict__ bv, const float* __restrict__ bs,
                                 float* __restrict__ dst){   // [L][1024]
    int idx = blockIdx.x * blockDim.x + threadIdx.x;
    if (idx >= NLAYERS * 1024) return;
    int l = idx >> 10, n = idx & 1023;
    int sel = n >> 8, nn = n & 255;
    const float* B = (sel == 0) ? bq : (sel == 1) ? bk : (sel == 2) ? bv : bs;
    dst[idx] = B[l * 256 + nn];
}

// ---- bf16 MFMA GEMM: C = [epi](A @ BT^T [+bias]) ----
// 128x128 tile, 256 thr (4 waves 2x2), K-step 32, mfma_f32_16x16x32_bf16.
// A: [M][K] bf16 (or f32, converted in staging). BT: [N][K] bf16.
template<bool A_F32, bool HAS_BIAS, bool GELU_EP, bool MASK_EP, bool WRITE_F32, bool WRITE_BF16>
__global__ __launch_bounds__(256)
void mfma_gemm(const void* __restrict__ Av, const bf16_t* __restrict__ BT,
               float* __restrict__ Cf, bf16_t* __restrict__ Cb,
               int Ncols, int K,
               const float* __restrict__ bias, const float* __restrict__ mask)
{
    __shared__ bf16_t As[128][40];   // padded: 80B rows -> ~2-way max on frag reads
    __shared__ bf16_t Bs[128][40];
    const int tid  = threadIdx.x;
    const int rowBase = blockIdx.y << 7;
    const int colBase = blockIdx.x << 7;
    const int lane = tid & 63;
    const int wave = tid >> 6;
    const int wm = wave >> 1, wn = wave & 1;
    const int lhi = lane >> 4, llo = lane & 15;
    const int r0 = tid >> 2;            // 0..63
    const int q0 = (tid & 3) << 3;      // 0,8,16,24

    f32x4v acc[4][4];
#pragma unroll
    for (int m = 0; m < 4; m++)
#pragma unroll
        for (int n = 0; n < 4; n++)
            acc[m][n] = (f32x4v){0.f, 0.f, 0.f, 0.f};

    const int nk = K >> 5;
    for (int ks = 0; ks < nk; ks++){
        const int k0 = ks << 5;
        if constexpr (A_F32){
            const float* Ap = (const float*)Av;
#pragma unroll
            for (int half = 0; half < 2; half++){
                int r = r0 + half * 64;
                const float* p = Ap + (size_t)(rowBase + r) * K + (k0 + q0);
                float4 a = *(const float4*)p;
                float4 b = *(const float4*)(p + 4);
                uint4 pk;
                pk.x = pack2(a.x, a.y); pk.y = pack2(a.z, a.w);
                pk.z = pack2(b.x, b.y); pk.w = pack2(b.z, b.w);
                *(uint4*)&As[r][q0] = pk;
            }
        } else {
            const bf16_t* Ap = (const bf16_t*)Av;
#pragma unroll
            for (int half = 0; half < 2; half++){
                int r = r0 + half * 64;
                *(uint4*)&As[r][q0] = *(const uint4*)(Ap + (size_t)(rowBase + r) * K + (k0 + q0));
            }
        }
#pragma unroll
        for (int half = 0; half < 2; half++){
            int r = r0 + half * 64;
            *(uint4*)&Bs[r][q0] = *(const uint4*)(BT + (size_t)(colBase + r) * K + (k0 + q0));
        }
        __syncthreads();
        bf16x8 af[4], bfr[4];
#pragma unroll
        for (int m = 0; m < 4; m++)
            af[m] = *(const bf16x8*)&As[(wm << 6) + (m << 4) + llo][lhi << 3];
#pragma unroll
        for (int n = 0; n < 4; n++)
            bfr[n] = *(const bf16x8*)&Bs[(wn << 6) + (n << 4) + llo][lhi << 3];
#pragma unroll
        for (int m = 0; m < 4; m++)
#pragma unroll
            for (int n = 0; n < 4; n++)
                acc[m][n] = __builtin_amdgcn_mfma_f32_16x16x32_bf16(af[m], bfr[n], acc[m][n], 0, 0, 0);
        __syncthreads();
    }

    // C/D layout (verified m89): col = lane&15, row = (lane>>4)*4 + reg
#pragma unroll
    for (int m = 0; m < 4; m++){
        const int rowb = rowBase + (wm << 6) + (m << 4) + (lhi << 2);
#pragma unroll
        for (int n = 0; n < 4; n++){
            const int col = colBase + (wn << 6) + (n << 4) + llo;
            float bv = 0.f;
            if constexpr (HAS_BIAS) bv = bias[col];
#pragma unroll
            for (int r = 0; r < 4; r++){
                float v = acc[m][n][r] + bv;
                if constexpr (GELU_EP) v = gelu_exact(v);
                if constexpr (MASK_EP) v *= mask[rowb + r];
                if constexpr (WRITE_F32) Cf[(size_t)(rowb + r) * Ncols + col] = v;
                if constexpr (WRITE_BF16) Cb[(size_t)(rowb + r) * Ncols + col] = f2bf(v);
            }
        }
    }
}

// ---- attention + fused beta gate: S = h + beta*xr + (1-beta)*attn_out ----
// QKVS layout per node: [q(256) | k(256) | v(256) | xr(256)]
__global__ __launch_bounds__(256)
void attn_beta_kernel(const bf16_t* __restrict__ QKVS, const float* __restrict__ h,
                      const int* __restrict__ rowstart, const int* __restrict__ eidx,
                      const int* __restrict__ src, const int* __restrict__ etype,
                      const float* __restrict__ eproj, const float* __restrict__ Wb,
                      float* __restrict__ S)
{
    int node = blockIdx.x;
    int wave = threadIdx.x >> 6, lane = threadIdx.x & 63;
    int fdim = (wave << 6) + lane;
    __shared__ float sh_a[4][256];
    __shared__ int   sh_e[256];
    __shared__ float sh_red[4];
    __shared__ float sh_beta;
    int s0 = rowstart[node];
    int deg = rowstart[node + 1] - s0;
    if (deg > 256) deg = 256;
    if (deg < 0) deg = 0;
    if (threadIdx.x < deg){
        int e = eidx[s0 + threadIdx.x];
        int sv = src[e]; if (sv < 0 || sv >= NN) sv = 0;
        sh_e[threadIdx.x] = (sv << 3) | (etype[e] & 7);
    }
    __syncthreads();
    float q = bf2f(QKVS[(size_t)node * 1024 + fdim]);
    float ep[NETT];
#pragma unroll
    for (int t = 0; t < NETT; t++) ep[t] = eproj[t * DD + fdim];
    float m = -1e30f;
    for (int i = 0; i < deg; i++){
        int pk = sh_e[i];
        int s = pk >> 3, t = pk & 7;
        float kv = bf2f(QKVS[(size_t)s * 1024 + 256 + fdim]) + ep[t];
        float d = q * kv;
#pragma unroll
        for (int off = 32; off; off >>= 1) d += __shfl_xor(d, off);
        d *= 0.125f;  // 1/sqrt(64)
        if (lane == 0) sh_a[wave][i] = d;
        m = fmaxf(m, d);
    }
    float den = 0.f;
    for (int i = 0; i < deg; i++){
        float ex = expf(sh_a[wave][i] - m);
        if (lane == 0) sh_a[wave][i] = ex;
        den += ex;
    }
    float invden = (deg > 0) ? 1.f / den : 0.f;
    float acc = 0.f;
    for (int i = 0; i < deg; i++){
        int pk = sh_e[i];
        int s = pk >> 3, t = pk & 7;
        float vv = bf2f(QKVS[(size_t)s * 1024 + 512 + fdim]) + ep[t];
        acc += sh_a[wave][i] * invden * vv;
    }
    float xr = bf2f(QKVS[(size_t)node * 1024 + 768 + fdim]);
    float part = acc * Wb[fdim] + xr * Wb[256 + fdim] + (acc - xr) * Wb[512 + fdim];
    part = wave_reduce_sum(part);
    if (lane == 0) sh_red[wave] = part;
    __syncthreads();
    if (threadIdx.x == 0){
        float p = sh_red[0] + sh_red[1] + sh_red[2] + sh_red[3];
        sh_beta = 1.f / (1.f + expf(-p));
    }
    __syncthreads();
    float beta = sh_beta;
    S[(size_t)node * DD + fdim] = h[(size_t)node * DD + fdim] + beta * xr + (1.f - beta) * acc;
}

// ---- GraphNorm (per graph, per dim over 128 nodes) + exact GELU -> h f32 ----
__global__ __launch_bounds__(256)
void graphnorm_gelu_kernel(const float* __restrict__ xin, const float* __restrict__ w,
                           const float* __restrict__ b, const float* __restrict__ ms,
                           float* __restrict__ hout)
{
    int g = blockIdx.x, d = threadIdx.x;
    const float* base = xin + (size_t)g * LL * DD + d;
    float s = 0.f;
    for (int n = 0; n < LL; n++) s += base[n * DD];
    float sub = s * (1.f / LL) * ms[d];
    float var = 0.f;
    for (int n = 0; n < LL; n++){ float t = base[n * DD] - sub; var += t * t; }
    var *= (1.f / LL);
    float rs = rsqrtf(var + 1e-5f);
    float wd = w[d], bd = b[d];
    float* ob = hout + (size_t)g * LL * DD + d;
    for (int n = 0; n < LL; n++){
        float t = (base[n * DD] - sub) * rs * wd + bd;
        ob[n * DD] = gelu_exact(t);
    }
}

// ---- final: out = LN(h + ff) * mask  (ff aliases outp; per-thread in-place safe) ----
__global__ __launch_bounds__(256)
void final_ln_kernel(const float* __restrict__ h, const float* __restrict__ ff,
                     const float* __restrict__ g, const float* __restrict__ b,
                     const float* __restrict__ mask, float* __restrict__ outp)
{
    int wave = threadIdx.x >> 6, lane = threadIdx.x & 63;
    int node = (blockIdx.x << 2) + wave;
    int d0 = lane << 2;
    float4 hv = *(const float4*)(h  + (size_t)node * DD + d0);
    float4 fv = *(const float4*)(ff + (size_t)node * DD + d0);
    float4 v; v.x = hv.x + fv.x; v.y = hv.y + fv.y; v.z = hv.z + fv.z; v.w = hv.w + fv.w;
    float s  = v.x + v.y + v.z + v.w;
    float sq = v.x*v.x + v.y*v.y + v.z*v.z + v.w*v.w;
    s = wave_reduce_sum(s); sq = wave_reduce_sum(sq);
    float mean = s * (1.f / DD);
    float var  = sq * (1.f / DD) - mean * mean;
    float rs = rsqrtf(var + 1e-5f);
    float mk = mask[node];
    float4 g4 = *(const float4*)(g + d0), b4 = *(const float4*)(b + d0);
    float4 r;
    r.x = ((v.x - mean) * rs * g4.x + b4.x) * mk;
    r.y = ((v.y - mean) * rs * g4.y + b4.y) * mk;
    r.z = ((v.z - mean) * rs * g4.z + b4.z) * mk;
    r.w = ((v.w - mean) * rs * g4.w + b4.w) * mk;
    *(float4*)(outp + (size_t)node * DD + d0) = r;
}

extern "C" void kernel_launch(void* const* d_in, const int* in_sizes, int n_in,
                              void* d_out, int out_size, void* d_ws, size_t ws_size,
                              hipStream_t stream)
{
    if (n_in < 33) return;
    if (in_sizes[0] != NN * DLLM) return;
    if (in_sizes[3] != 2 * NE) return;
    if (in_sizes[8] != DLLM * DD) return;
    if (in_sizes[27] != DD * 4 * DD) return;
    if (out_size != NN * DD) return;

    const float* atom_llm    = (const float*)d_in[0];
    const float* atom_onehot = (const float*)d_in[1];
    const float* mask        = (const float*)d_in[2];
    const int*   edge_index  = (const int*)d_in[3];
    const int*   etype       = (const int*)d_in[4];
    const float* ln_llm_g    = (const float*)d_in[6];
    const float* ln_llm_b    = (const float*)d_in[7];
    const float* W_llm       = (const float*)d_in[8];
    const float* b_llm       = (const float*)d_in[9];
    const float* W_oh        = (const float*)d_in[10];
    const float* edge_emb    = (const float*)d_in[11];
    const float* edge_ln_g   = (const float*)d_in[12];
    const float* edge_ln_b   = (const float*)d_in[13];
    const float* Wq          = (const float*)d_in[14];
    const float* bq          = (const float*)d_in[15];
    const float* Wk          = (const float*)d_in[16];
    const float* bk          = (const float*)d_in[17];
    const float* Wv          = (const float*)d_in[18];
    const float* bv          = (const float*)d_in[19];
    const float* We          = (const float*)d_in[20];
    const float* Ws          = (const float*)d_in[21];
    const float* bs          = (const float*)d_in[22];
    const float* Wb          = (const float*)d_in[23];
    const float* gn_w        = (const float*)d_in[24];
    const float* gn_b        = (const float*)d_in[25];
    const float* gn_ms       = (const float*)d_in[26];
    const float* W1          = (const float*)d_in[27];
    const float* b1          = (const float*)d_in[28];
    const float* W2          = (const float*)d_in[29];
    const float* b2          = (const float*)d_in[30];
    const float* out_ln_g    = (const float*)d_in[31];
    const float* out_ln_b    = (const float*)d_in[32];

    const int* srcv = edge_index;
    const int* dstv = edge_index + NE;

    char* ws = (char*)d_ws;
    size_t off = 0;
    auto alloc = [&](size_t bytes) -> char* {
        char* p = ws + off; off += (bytes + 255) / 256 * 256; return p;
    };
    float*  h    = (float*)alloc((size_t)NN * DD * sizeof(float));      // 33.5 MB
    bf16_t* reg3 = (bf16_t*)alloc((size_t)NN * 1088 * sizeof(bf16_t));  // 71.3 MB: xln / qkvs / t1
    bf16_t* wt_in   = (bf16_t*)alloc((size_t)256 * 1088 * sizeof(bf16_t));
    bf16_t* wt_qkvs = (bf16_t*)alloc((size_t)NLAYERS * 1024 * 256 * sizeof(bf16_t));
    bf16_t* wt_w1   = (bf16_t*)alloc((size_t)1024 * 256 * sizeof(bf16_t));
    bf16_t* wt_w2   = (bf16_t*)alloc((size_t)256 * 1024 * sizeof(bf16_t));
    float*  biasp   = (float*)alloc((size_t)NLAYERS * 1024 * sizeof(float));
    float*  eproj   = (float*)alloc((size_t)NLAYERS * NETT * DD * sizeof(float));
    int* cnt      = (int*)alloc((size_t)NN * sizeof(int));
    int* rowstart = (int*)alloc((size_t)(NN + 1) * sizeof(int));
    int* cursor   = (int*)alloc((size_t)NN * sizeof(int));
    int* eidx     = (int*)alloc((size_t)NE * sizeof(int));
    bf16_t* xln  = reg3;      // [NN][1088]
    bf16_t* qkvs = reg3;      // [NN][1024] (after xln dead)
    bf16_t* t1   = reg3;      // [NN][1024] (after qkvs dead)
    float*  S    = (float*)d_out;  // f32 scratch: beta out / gnorm in / FFN t2

    if (ws_size < off) return;  // clean bail instead of OOB fault

    // CSR build
    zero_kernel<<<NN / 256, 256, 0, stream>>>(cnt, NN);
    count_kernel<<<NE / 256, 256, 0, stream>>>(dstv, cnt);
    scan_kernel<<<1, 1024, 0, stream>>>(cnt, rowstart, cursor);
    scatter_kernel<<<NE / 256, 256, 0, stream>>>(dstv, cursor, eidx);

    // precompute: LN+concat, edge proj table, weight conversion
    ln_concat_kernel<<<NN / 4, 256, 0, stream>>>(atom_llm, atom_onehot, ln_llm_g, ln_llm_b, xln);
    edgeproj_kernel<<<NLAYERS * NETT, 256, 0, stream>>>(edge_emb, edge_ln_g, edge_ln_b, We, eproj);
    wcvt_in_kernel<<<(256 * 1088 + 255) / 256, 256, 0, stream>>>(W_llm, W_oh, wt_in);
    wcvt_qkvs_kernel<<<(NLAYERS * 1024 * 256) / 256, 256, 0, stream>>>(Wq, Wk, Wv, Ws, wt_qkvs);
    wcvt_w1_kernel<<<(1024 * 256) / 256, 256, 0, stream>>>(W1, wt_w1);
    wcvt_w2_kernel<<<(256 * 1024) / 256, 256, 0, stream>>>(W2, wt_w2);
    pack_bias_kernel<<<(NLAYERS * 1024) / 256, 256, 0, stream>>>(bq, bk, bv, bs, biasp);

    // input proj: h = (xln @ [W_llm;W_oh] + b_llm) * mask   [f32]
    {
        dim3 grid(DD / 128, NN / 128);
        mfma_gemm<false, true, false, true, true, false><<<grid, 256, 0, stream>>>(
            xln, wt_in, h, nullptr, DD, 1088, b_llm, mask);
    }

    for (int l = 0; l < NLAYERS; l++){
        // qkvs = h @ [Wq|Wk|Wv|Ws] + bias   [bf16, N=1024]
        dim3 grid(1024 / 128, NN / 128);
        mfma_gemm<true, true, false, false, false, true><<<grid, 256, 0, stream>>>(
            h, wt_qkvs + (size_t)l * 1024 * 256, nullptr, qkvs, 1024, DD,
            biasp + (size_t)l * 1024, nullptr);

        attn_beta_kernel<<<NN, 256, 0, stream>>>(qkvs, h, rowstart, eidx, srcv, etype,
                                                 eproj + (size_t)l * NETT * DD,
                                                 Wb + (size_t)l * 768, S);

        graphnorm_gelu_kernel<<<NB, 256, 0, stream>>>(S, gn_w + l * DD, gn_b + l * DD,
                                                      gn_ms + l * DD, h);
    }

    // FFN: t1 = gelu(h @ W1 + b1) [bf16]; S = t1 @ W2 + b2 [f32]; out = LN(h + S) * mask
    {
        dim3 grid1(1024 / 128, NN / 128);
        mfma_gemm<true, true, true, false, false, true><<<grid1, 256, 0, stream>>>(
            h, wt_w1, nullptr, t1, 1024, DD, b1, nullptr);
        dim3 grid2(DD / 128, NN / 128);
        mfma_gemm<false, true, false, false, true, false><<<grid2, 256, 0, stream>>>(
            t1, wt_w2, S, nullptr, DD, 1024, b2, nullptr);
        final_ln_kernel<<<NN / 4, 256, 0, stream>>>(h, S, out_ln_g, out_ln_b, mask,
                                                    (float*)d_out);
    }
}

// Round 6
// 1130.268 us; speedup vs baseline: 2.3006x; 1.1182x over previous
//
#include <hip/hip_runtime.h>
#include <math.h>

#define NB      256
#define LL      128
#define NN      32768
#define DLLM    1024
#define COH     64
#define DD      256
#define NLAYERS 4
#define EDIM    64
#define NETT    8
#define NE      131072
#define CHUNK   16

typedef unsigned short bf16_t;
typedef __bf16 bf16x8 __attribute__((ext_vector_type(8)));
typedef float f32x4v __attribute__((ext_vector_type(4)));

__device__ __forceinline__ float bf2f(bf16_t u){
    return __uint_as_float(((unsigned int)u) << 16);
}
__device__ __forceinline__ bf16_t f2bf(float f){
    unsigned int x = __float_as_uint(f);
    return (bf16_t)((x + 0x7fffu + ((x >> 16) & 1u)) >> 16);
}
__device__ __forceinline__ unsigned pack2(float a, float b){
    return (unsigned)f2bf(a) | ((unsigned)f2bf(b) << 16);
}
__device__ __forceinline__ float gelu_exact(float x){
    return 0.5f * x * (1.0f + erff(x * 0.70710678118654752440f));
}
__device__ __forceinline__ float wave_reduce_sum(float v){
#pragma unroll
    for (int off = 32; off; off >>= 1) v += __shfl_xor(v, off);
    return v;
}

__global__ void zero_kernel(int* __restrict__ p, int n){
    int i = blockIdx.x * blockDim.x + threadIdx.x;
    if (i < n) p[i] = 0;
}

// ---- LN(atom_llm)*g+b -> bf16, concat onehot -> xln [NN][1088] ----
__global__ __launch_bounds__(256)
void ln_concat_kernel(const float* __restrict__ A, const float* __restrict__ onehot,
                      const float* __restrict__ g, const float* __restrict__ b,
                      bf16_t* __restrict__ xln){
    int wave = threadIdx.x >> 6, lane = threadIdx.x & 63;
    int row = (blockIdx.x << 2) + wave;
    const float* p = A + (size_t)row * DLLM;
    float4 v[4];
    float s = 0.f, sq = 0.f;
#pragma unroll
    for (int c = 0; c < 4; c++){
        v[c] = *(const float4*)(p + c * 256 + (lane << 2));
        s  += v[c].x + v[c].y + v[c].z + v[c].w;
        sq += v[c].x*v[c].x + v[c].y*v[c].y + v[c].z*v[c].z + v[c].w*v[c].w;
    }
    s = wave_reduce_sum(s); sq = wave_reduce_sum(sq);
    float mean = s * (1.0f / DLLM);
    float var  = sq * (1.0f / DLLM) - mean * mean;
    float rstd = rsqrtf(var + 1e-5f);
    bf16_t* out = xln + (size_t)row * 1088;
#pragma unroll
    for (int c = 0; c < 4; c++){
        float4 g4 = *(const float4*)(g + c * 256 + (lane << 2));
        float4 b4 = *(const float4*)(b + c * 256 + (lane << 2));
        float rx = (v[c].x - mean) * rstd * g4.x + b4.x;
        float ry = (v[c].y - mean) * rstd * g4.y + b4.y;
        float rz = (v[c].z - mean) * rstd * g4.z + b4.z;
        float rw = (v[c].w - mean) * rstd * g4.w + b4.w;
        ushort4 u; u.x = f2bf(rx); u.y = f2bf(ry); u.z = f2bf(rz); u.w = f2bf(rw);
        *(ushort4*)(out + c * 256 + (lane << 2)) = u;
    }
    out[1024 + lane] = f2bf(onehot[(size_t)row * COH + lane]);
}

// ---- eproj[l][t][:] = LN(edge_emb[t]) @ We[l] ----
__global__ __launch_bounds__(256)
void edgeproj_kernel(const float* __restrict__ edge_emb,
                     const float* __restrict__ lg, const float* __restrict__ lb,
                     const float* __restrict__ We, float* __restrict__ eproj){
    int l = blockIdx.x >> 3, t = blockIdx.x & 7;
    __shared__ float ea[EDIM];
    int tid = threadIdx.x;
    if (tid < 64){
        float v = edge_emb[t * EDIM + tid];
        float s = v, sq = v * v;
#pragma unroll
        for (int off = 32; off; off >>= 1){ s += __shfl_xor(s, off); sq += __shfl_xor(sq, off); }
        float mean = s * (1.f/64.f);
        float var  = sq * (1.f/64.f) - mean * mean;
        float rstd = rsqrtf(var + 1e-5f);
        ea[tid] = (v - mean) * rstd * lg[tid] + lb[tid];
    }
    __syncthreads();
    const float* W = We + (size_t)l * EDIM * DD;
    float s = 0.f;
#pragma unroll
    for (int k = 0; k < EDIM; k++) s += ea[k] * W[k * DD + tid];
    eproj[((l << 3) + t) * DD + tid] = s;
}

// ---- CSR build over dst (epack = srcLocal<<3 | etype) ----
__global__ void count_kernel(const int* __restrict__ dst, int* __restrict__ cnt){
    int e = blockIdx.x * blockDim.x + threadIdx.x;
    if (e < NE){
        int d = dst[e];
        if (d >= 0 && d < NN) atomicAdd(&cnt[d], 1);
    }
}

__global__ __launch_bounds__(1024)
void scan_kernel(const int* __restrict__ cnt, int* __restrict__ rowstart, int* __restrict__ cursor){
    __shared__ int sh[1024];
    int tid = threadIdx.x;
    int carry = 0;
    for (int base = 0; base < NN; base += 1024){
        int v = cnt[base + tid];
        sh[tid] = v; __syncthreads();
        for (int off = 1; off < 1024; off <<= 1){
            int t = (tid >= off) ? sh[tid - off] : 0;
            __syncthreads();
            sh[tid] += t;
            __syncthreads();
        }
        int excl = carry + sh[tid] - v;
        rowstart[base + tid] = excl;
        cursor[base + tid]   = excl;
        carry += sh[1023];
        __syncthreads();
    }
    if (tid == 0) rowstart[NN] = carry;
}

__global__ void scatter_kernel(const int* __restrict__ dst, const int* __restrict__ src,
                               const int* __restrict__ etype, int* __restrict__ cursor,
                               int* __restrict__ epack){
    int e = blockIdx.x * blockDim.x + threadIdx.x;
    if (e < NE){
        int d = dst[e];
        if (d >= 0 && d < NN){
            int p = atomicAdd(&cursor[d], 1);
            if (p >= 0 && p < NE){
                int sv = src[e]; if (sv < 0 || sv >= NN) sv = 0;
                epack[p] = ((sv & 127) << 3) | (etype[e] & 7);
            }
        }
    }
}

// ---- weight conversion / transposition to bf16 ----
__global__ void wcvt_in_kernel(const float* __restrict__ Wllm, const float* __restrict__ Woh,
                               bf16_t* __restrict__ dst){   // [256][1088]
    int idx = blockIdx.x * blockDim.x + threadIdx.x;
    if (idx >= 256 * 1088) return;
    int n = idx / 1088, k = idx % 1088;
    float v = (k < 1024) ? Wllm[(size_t)k * 256 + n] : Woh[(size_t)(k - 1024) * 256 + n];
    dst[idx] = f2bf(v);
}

__global__ void wcvt_qkvs_kernel(const float* __restrict__ Wq, const float* __restrict__ Wk,
                                 const float* __restrict__ Wv, const float* __restrict__ Ws,
                                 bf16_t* __restrict__ dst){  // [L][1024][256]
    int idx = blockIdx.x * blockDim.x + threadIdx.x;
    if (idx >= NLAYERS * 1024 * 256) return;
    int l = idx >> 18, rem = idx & 262143;
    int n = rem >> 8, k = rem & 255;
    int sel = n >> 8, nn = n & 255;
    const float* W = (sel == 0) ? Wq : (sel == 1) ? Wk : (sel == 2) ? Wv : Ws;
    dst[idx] = f2bf(W[(size_t)l * 65536 + (size_t)k * 256 + nn]);
}

__global__ void wcvt_w1_kernel(const float* __restrict__ W1, bf16_t* __restrict__ dst){ // [1024][256]
    int idx = blockIdx.x * blockDim.x + threadIdx.x;
    if (idx >= 1024 * 256) return;
    int n = idx >> 8, k = idx & 255;
    dst[idx] = f2bf(W1[(size_t)k * 1024 + n]);
}

__global__ void wcvt_w2_kernel(const float* __restrict__ W2, bf16_t* __restrict__ dst){ // [256][1024]
    int idx = blockIdx.x * blockDim.x + threadIdx.x;
    if (idx >= 256 * 1024) return;
    int n = idx >> 10, k = idx & 1023;
    dst[idx] = f2bf(W2[(size_t)k * 256 + n]);
}

__global__ void pack_bias_kernel(const float* __restrict__ bq, const float* __restrict__ bk,
                                 const float* __restrict__ bv, const float* __restrict__ bs,
                                 float* __restrict__ dst){   // [L][1024]
    int idx = blockIdx.x * blockDim.x + threadIdx.x;
    if (idx >= NLAYERS * 1024) return;
    int l = idx >> 10, n = idx & 1023;
    int sel = n >> 8, nn = n & 255;
    const float* B = (sel == 0) ? bq : (sel == 1) ? bk : (sel == 2) ? bv : bs;
    dst[idx] = B[l * 256 + nn];
}

// ---- bf16 MFMA GEMM: C = [epi](A @ BT^T [+bias]) ----
// 128x128 tile, 256 thr (4 waves 2x2), K-step 32, mfma_f32_16x16x32_bf16.
template<bool A_F32, bool HAS_BIAS, bool GELU_EP, bool MASK_EP, bool WRITE_F32, bool WRITE_BF16>
__global__ __launch_bounds__(256)
void mfma_gemm(const void* __restrict__ Av, const bf16_t* __restrict__ BT,
               float* __restrict__ Cf, bf16_t* __restrict__ Cb,
               int Ncols, int K,
               const float* __restrict__ bias, const float* __restrict__ mask)
{
    __shared__ bf16_t As[128][40];
    __shared__ bf16_t Bs[128][40];
    const int tid  = threadIdx.x;
    const int rowBase = blockIdx.y << 7;
    const int colBase = blockIdx.x << 7;
    const int lane = tid & 63;
    const int wave = tid >> 6;
    const int wm = wave >> 1, wn = wave & 1;
    const int lhi = lane >> 4, llo = lane & 15;
    const int r0 = tid >> 2;
    const int q0 = (tid & 3) << 3;

    f32x4v acc[4][4];
#pragma unroll
    for (int m = 0; m < 4; m++)
#pragma unroll
        for (int n = 0; n < 4; n++)
            acc[m][n] = (f32x4v){0.f, 0.f, 0.f, 0.f};

    const int nk = K >> 5;
    for (int ks = 0; ks < nk; ks++){
        const int k0 = ks << 5;
        if constexpr (A_F32){
            const float* Ap = (const float*)Av;
#pragma unroll
            for (int half = 0; half < 2; half++){
                int r = r0 + half * 64;
                const float* p = Ap + (size_t)(rowBase + r) * K + (k0 + q0);
                float4 a = *(const float4*)p;
                float4 b = *(const float4*)(p + 4);
                uint4 pk;
                pk.x = pack2(a.x, a.y); pk.y = pack2(a.z, a.w);
                pk.z = pack2(b.x, b.y); pk.w = pack2(b.z, b.w);
                *(uint4*)&As[r][q0] = pk;
            }
        } else {
            const bf16_t* Ap = (const bf16_t*)Av;
#pragma unroll
            for (int half = 0; half < 2; half++){
                int r = r0 + half * 64;
                *(uint4*)&As[r][q0] = *(const uint4*)(Ap + (size_t)(rowBase + r) * K + (k0 + q0));
            }
        }
#pragma unroll
        for (int half = 0; half < 2; half++){
            int r = r0 + half * 64;
            *(uint4*)&Bs[r][q0] = *(const uint4*)(BT + (size_t)(colBase + r) * K + (k0 + q0));
        }
        __syncthreads();
        bf16x8 af[4], bfr[4];
#pragma unroll
        for (int m = 0; m < 4; m++)
            af[m] = *(const bf16x8*)&As[(wm << 6) + (m << 4) + llo][lhi << 3];
#pragma unroll
        for (int n = 0; n < 4; n++)
            bfr[n] = *(const bf16x8*)&Bs[(wn << 6) + (n << 4) + llo][lhi << 3];
#pragma unroll
        for (int m = 0; m < 4; m++)
#pragma unroll
            for (int n = 0; n < 4; n++)
                acc[m][n] = __builtin_amdgcn_mfma_f32_16x16x32_bf16(af[m], bfr[n], acc[m][n], 0, 0, 0);
        __syncthreads();
    }

#pragma unroll
    for (int m = 0; m < 4; m++){
        const int rowb = rowBase + (wm << 6) + (m << 4) + (lhi << 2);
#pragma unroll
        for (int n = 0; n < 4; n++){
            const int col = colBase + (wn << 6) + (n << 4) + llo;
            float bv = 0.f;
            if constexpr (HAS_BIAS) bv = bias[col];
#pragma unroll
            for (int r = 0; r < 4; r++){
                float v = acc[m][n][r] + bv;
                if constexpr (GELU_EP) v = gelu_exact(v);
                if constexpr (MASK_EP) v *= mask[rowb + r];
                if constexpr (WRITE_F32) Cf[(size_t)(rowb + r) * Ncols + col] = v;
                if constexpr (WRITE_BF16) Cb[(size_t)(rowb + r) * Ncols + col] = f2bf(v);
            }
        }
    }
}

// ---- per-GRAPH attention + beta gate: LDS-staged K/V, chunked online softmax ----
// block = one graph (128 nodes), 512 threads = 8 waves, each wave owns 16 dst nodes.
// lane l owns dims 4l..4l+3 (head = l>>4 automatically). QKVS: [node][q|k|v|xr].
__global__ __launch_bounds__(512)
void attn_graph_kernel(const bf16_t* __restrict__ QKVS, const float* __restrict__ h,
                       const int* __restrict__ rowstart, const int* __restrict__ epack,
                       const float* __restrict__ eproj, const float* __restrict__ Wb,
                       float* __restrict__ S)
{
    __shared__ bf16_t Kl[128][256];     // 64 KB
    __shared__ bf16_t Vl[128][256];     // 64 KB
    __shared__ float  epl[8][256];      // 8 KB
    __shared__ float  al[8][CHUNK][4];  // 2 KB
    const int g = blockIdx.x;
    const int tid = threadIdx.x;
    const int wave = tid >> 6, lane = tid & 63;
    const int hgrp = lane >> 4;
    const int d4 = lane << 2;
    const size_t gbase = (size_t)g * 128 * 1024;

    // stage K, V, eproj
    for (int i = tid; i < 128 * 32; i += 512){
        int n = i >> 5, c = (i & 31) << 3;
        *(uint4*)&Kl[n][c] = *(const uint4*)(QKVS + gbase + (size_t)n * 1024 + 256 + c);
        *(uint4*)&Vl[n][c] = *(const uint4*)(QKVS + gbase + (size_t)n * 1024 + 512 + c);
    }
    for (int i = tid; i < 8 * 256; i += 512) epl[i >> 8][i & 255] = eproj[i];
    __syncthreads();

    // beta-gate weights (node-independent): hoist
    float4 w0 = *(const float4*)(Wb + d4);
    float4 w1 = *(const float4*)(Wb + 256 + d4);
    float4 w2 = *(const float4*)(Wb + 512 + d4);

    for (int ni = 0; ni < 16; ni++){
        int nl = (wave << 4) + ni;
        int node = (g << 7) + nl;
        int s0 = rowstart[node];
        int deg = rowstart[node + 1] - s0;
        if (deg < 0) deg = 0;
        ushort4 qu = *(const ushort4*)(QKVS + gbase + (size_t)nl * 1024 + d4);
        float q0 = bf2f(qu.x), q1 = bf2f(qu.y), q2 = bf2f(qu.z), q3 = bf2f(qu.w);
        float m = -1e30f, den = 0.f;
        float v0 = 0.f, v1 = 0.f, v2 = 0.f, v3 = 0.f;
        for (int c0 = 0; c0 < deg; c0 += CHUNK){
            int ce = deg - c0; if (ce > CHUNK) ce = CHUNK;
            for (int i = 0; i < ce; i++){
                int pk = epack[s0 + c0 + i];
                int sl = pk >> 3, t = pk & 7;
                ushort4 ku = *(const ushort4*)&Kl[sl][d4];
                float4 ev = *(const float4*)&epl[t][d4];
                float d = q0 * (bf2f(ku.x) + ev.x) + q1 * (bf2f(ku.y) + ev.y)
                        + q2 * (bf2f(ku.z) + ev.z) + q3 * (bf2f(ku.w) + ev.w);
                d += __shfl_xor(d, 1); d += __shfl_xor(d, 2);
                d += __shfl_xor(d, 4); d += __shfl_xor(d, 8);
                if ((lane & 15) == 0) al[wave][i][hgrp] = d * 0.125f;
            }
            float cm = -1e30f;
            for (int i = 0; i < ce; i++) cm = fmaxf(cm, al[wave][i][hgrp]);
            float mnew = fmaxf(m, cm);
            float scale = expf(m - mnew);
            den *= scale; v0 *= scale; v1 *= scale; v2 *= scale; v3 *= scale;
            for (int i = 0; i < ce; i++){
                int pk = epack[s0 + c0 + i];
                int sl = pk >> 3, t = pk & 7;
                float w = expf(al[wave][i][hgrp] - mnew);
                den += w;
                ushort4 vu = *(const ushort4*)&Vl[sl][d4];
                float4 ev = *(const float4*)&epl[t][d4];
                v0 = fmaf(w, bf2f(vu.x) + ev.x, v0);
                v1 = fmaf(w, bf2f(vu.y) + ev.y, v1);
                v2 = fmaf(w, bf2f(vu.z) + ev.z, v2);
                v3 = fmaf(w, bf2f(vu.w) + ev.w, v3);
            }
            m = mnew;
        }
        float inv = (den > 0.f) ? 1.f / den : 0.f;
        v0 *= inv; v1 *= inv; v2 *= inv; v3 *= inv;
        ushort4 xu = *(const ushort4*)(QKVS + gbase + (size_t)nl * 1024 + 768 + d4);
        float x0 = bf2f(xu.x), x1 = bf2f(xu.y), x2 = bf2f(xu.z), x3 = bf2f(xu.w);
        float part = v0*w0.x + v1*w0.y + v2*w0.z + v3*w0.w
                   + x0*w1.x + x1*w1.y + x2*w1.z + x3*w1.w
                   + (v0-x0)*w2.x + (v1-x1)*w2.y + (v2-x2)*w2.z + (v3-x3)*w2.w;
        part = wave_reduce_sum(part);
        float beta = 1.f / (1.f + expf(-part));
        float4 hv = *(const float4*)(h + ((size_t)node << 8) + d4);
        float4 r;
        r.x = hv.x + beta * x0 + (1.f - beta) * v0;
        r.y = hv.y + beta * x1 + (1.f - beta) * v1;
        r.z = hv.z + beta * x2 + (1.f - beta) * v2;
        r.w = hv.w + beta * x3 + (1.f - beta) * v3;
        *(float4*)(S + ((size_t)node << 8) + d4) = r;
    }
}

// ---- GraphNorm (per graph, per dim over 128 nodes) + exact GELU -> h f32 ----
__global__ __launch_bounds__(256)
void graphnorm_gelu_kernel(const float* __restrict__ xin, const float* __restrict__ w,
                           const float* __restrict__ b, const float* __restrict__ ms,
                           float* __restrict__ hout)
{
    int g = blockIdx.x, d = threadIdx.x;
    const float* base = xin + (size_t)g * LL * DD + d;
    float s = 0.f;
    for (int n = 0; n < LL; n++) s += base[n * DD];
    float sub = s * (1.f / LL) * ms[d];
    float var = 0.f;
    for (int n = 0; n < LL; n++){ float t = base[n * DD] - sub; var += t * t; }
    var *= (1.f / LL);
    float rs = rsqrtf(var + 1e-5f);
    float wd = w[d], bd = b[d];
    float* ob = hout + (size_t)g * LL * DD + d;
    for (int n = 0; n < LL; n++){
        float t = (base[n * DD] - sub) * rs * wd + bd;
        ob[n * DD] = gelu_exact(t);
    }
}

// ---- final: out = LN(h + ff) * mask ----
__global__ __launch_bounds__(256)
void final_ln_kernel(const float* __restrict__ h, const float* __restrict__ ff,
                     const float* __restrict__ g, const float* __restrict__ b,
                     const float* __restrict__ mask, float* __restrict__ outp)
{
    int wave = threadIdx.x >> 6, lane = threadIdx.x & 63;
    int node = (blockIdx.x << 2) + wave;
    int d0 = lane << 2;
    float4 hv = *(const float4*)(h  + (size_t)node * DD + d0);
    float4 fv = *(const float4*)(ff + (size_t)node * DD + d0);
    float4 v; v.x = hv.x + fv.x; v.y = hv.y + fv.y; v.z = hv.z + fv.z; v.w = hv.w + fv.w;
    float s  = v.x + v.y + v.z + v.w;
    float sq = v.x*v.x + v.y*v.y + v.z*v.z + v.w*v.w;
    s = wave_reduce_sum(s); sq = wave_reduce_sum(sq);
    float mean = s * (1.f / DD);
    float var  = sq * (1.f / DD) - mean * mean;
    float rs = rsqrtf(var + 1e-5f);
    float mk = mask[node];
    float4 g4 = *(const float4*)(g + d0), b4 = *(const float4*)(b + d0);
    float4 r;
    r.x = ((v.x - mean) * rs * g4.x + b4.x) * mk;
    r.y = ((v.y - mean) * rs * g4.y + b4.y) * mk;
    r.z = ((v.z - mean) * rs * g4.z + b4.z) * mk;
    r.w = ((v.w - mean) * rs * g4.w + b4.w) * mk;
    *(float4*)(outp + (size_t)node * DD + d0) = r;
}

extern "C" void kernel_launch(void* const* d_in, const int* in_sizes, int n_in,
                              void* d_out, int out_size, void* d_ws, size_t ws_size,
                              hipStream_t stream)
{
    if (n_in < 33) return;
    if (in_sizes[0] != NN * DLLM) return;
    if (in_sizes[3] != 2 * NE) return;
    if (in_sizes[8] != DLLM * DD) return;
    if (in_sizes[27] != DD * 4 * DD) return;
    if (out_size != NN * DD) return;

    const float* atom_llm    = (const float*)d_in[0];
    const float* atom_onehot = (const float*)d_in[1];
    const float* mask        = (const float*)d_in[2];
    const int*   edge_index  = (const int*)d_in[3];
    const int*   etype       = (const int*)d_in[4];
    const float* ln_llm_g    = (const float*)d_in[6];
    const float* ln_llm_b    = (const float*)d_in[7];
    const float* W_llm       = (const float*)d_in[8];
    const float* b_llm       = (const float*)d_in[9];
    const float* W_oh        = (const float*)d_in[10];
    const float* edge_emb    = (const float*)d_in[11];
    const float* edge_ln_g   = (const float*)d_in[12];
    const float* edge_ln_b   = (const float*)d_in[13];
    const float* Wq          = (const float*)d_in[14];
    const float* bq          = (const float*)d_in[15];
    const float* Wk          = (const float*)d_in[16];
    const float* bk          = (const float*)d_in[17];
    const float* Wv          = (const float*)d_in[18];
    const float* bv          = (const float*)d_in[19];
    const float* We          = (const float*)d_in[20];
    const float* Ws          = (const float*)d_in[21];
    const float* bs          = (const float*)d_in[22];
    const float* Wb          = (const float*)d_in[23];
    const float* gn_w        = (const float*)d_in[24];
    const float* gn_b        = (const float*)d_in[25];
    const float* gn_ms       = (const float*)d_in[26];
    const float* W1          = (const float*)d_in[27];
    const float* b1          = (const float*)d_in[28];
    const float* W2          = (const float*)d_in[29];
    const float* b2          = (const float*)d_in[30];
    const float* out_ln_g    = (const float*)d_in[31];
    const float* out_ln_b    = (const float*)d_in[32];

    const int* srcv = edge_index;
    const int* dstv = edge_index + NE;

    char* ws = (char*)d_ws;
    size_t off = 0;
    auto alloc = [&](size_t bytes) -> char* {
        char* p = ws + off; off += (bytes + 255) / 256 * 256; return p;
    };
    float*  h    = (float*)alloc((size_t)NN * DD * sizeof(float));      // 33.5 MB
    bf16_t* reg3 = (bf16_t*)alloc((size_t)NN * 1088 * sizeof(bf16_t));  // 71.3 MB: xln / qkvs / t1
    bf16_t* wt_in   = (bf16_t*)alloc((size_t)256 * 1088 * sizeof(bf16_t));
    bf16_t* wt_qkvs = (bf16_t*)alloc((size_t)NLAYERS * 1024 * 256 * sizeof(bf16_t));
    bf16_t* wt_w1   = (bf16_t*)alloc((size_t)1024 * 256 * sizeof(bf16_t));
    bf16_t* wt_w2   = (bf16_t*)alloc((size_t)256 * 1024 * sizeof(bf16_t));
    float*  biasp   = (float*)alloc((size_t)NLAYERS * 1024 * sizeof(float));
    float*  eproj   = (float*)alloc((size_t)NLAYERS * NETT * DD * sizeof(float));
    int* cnt      = (int*)alloc((size_t)NN * sizeof(int));
    int* rowstart = (int*)alloc((size_t)(NN + 1) * sizeof(int));
    int* cursor   = (int*)alloc((size_t)NN * sizeof(int));
    int* epack    = (int*)alloc((size_t)NE * sizeof(int));
    bf16_t* xln  = reg3;      // [NN][1088]
    bf16_t* qkvs = reg3;      // [NN][1024]
    bf16_t* t1   = reg3;      // [NN][1024]
    float*  S    = (float*)d_out;

    if (ws_size < off) return;

    // CSR build
    zero_kernel<<<NN / 256, 256, 0, stream>>>(cnt, NN);
    count_kernel<<<NE / 256, 256, 0, stream>>>(dstv, cnt);
    scan_kernel<<<1, 1024, 0, stream>>>(cnt, rowstart, cursor);
    scatter_kernel<<<NE / 256, 256, 0, stream>>>(dstv, srcv, etype, cursor, epack);

    // precompute
    ln_concat_kernel<<<NN / 4, 256, 0, stream>>>(atom_llm, atom_onehot, ln_llm_g, ln_llm_b, xln);
    edgeproj_kernel<<<NLAYERS * NETT, 256, 0, stream>>>(edge_emb, edge_ln_g, edge_ln_b, We, eproj);
    wcvt_in_kernel<<<(256 * 1088 + 255) / 256, 256, 0, stream>>>(W_llm, W_oh, wt_in);
    wcvt_qkvs_kernel<<<(NLAYERS * 1024 * 256) / 256, 256, 0, stream>>>(Wq, Wk, Wv, Ws, wt_qkvs);
    wcvt_w1_kernel<<<(1024 * 256) / 256, 256, 0, stream>>>(W1, wt_w1);
    wcvt_w2_kernel<<<(256 * 1024) / 256, 256, 0, stream>>>(W2, wt_w2);
    pack_bias_kernel<<<(NLAYERS * 1024) / 256, 256, 0, stream>>>(bq, bk, bv, bs, biasp);

    // input proj: h = (xln @ [W_llm;W_oh] + b_llm) * mask   [f32]
    {
        dim3 grid(DD / 128, NN / 128);
        mfma_gemm<false, true, false, true, true, false><<<grid, 256, 0, stream>>>(
            xln, wt_in, h, nullptr, DD, 1088, b_llm, mask);
    }

    for (int l = 0; l < NLAYERS; l++){
        dim3 grid(1024 / 128, NN / 128);
        mfma_gemm<true, true, false, false, false, true><<<grid, 256, 0, stream>>>(
            h, wt_qkvs + (size_t)l * 1024 * 256, nullptr, qkvs, 1024, DD,
            biasp + (size_t)l * 1024, nullptr);

        attn_graph_kernel<<<NB, 512, 0, stream>>>(qkvs, h, rowstart, epack,
                                                  eproj + (size_t)l * NETT * DD,
                                                  Wb + (size_t)l * 768, S);

        graphnorm_gelu_kernel<<<NB, 256, 0, stream>>>(S, gn_w + l * DD, gn_b + l * DD,
                                                      gn_ms + l * DD, h);
    }

    // FFN
    {
        dim3 grid1(1024 / 128, NN / 128);
        mfma_gemm<true, true, true, false, false, true><<<grid1, 256, 0, stream>>>(
            h, wt_w1, nullptr, t1, 1024, DD, b1, nullptr);
        dim3 grid2(DD / 128, NN / 128);
        mfma_gemm<false, true, false, false, true, false><<<grid2, 256, 0, stream>>>(
            t1, wt_w2, S, nullptr, DD, 1024, b2, nullptr);
        final_ln_kernel<<<NN / 4, 256, 0, stream>>>(h, S, out_ln_g, out_ln_b, mask,
                                                    (float*)d_out);
    }
}

// Round 7
// 1078.336 us; speedup vs baseline: 2.4114x; 1.0482x over previous
//
#include <hip/hip_runtime.h>
#include <math.h>

#define NB      256
#define LL      128
#define NN      32768
#define DLLM    1024
#define COH     64
#define DD      256
#define NLAYERS 4
#define EDIM    64
#define NETT    8
#define NE      131072

typedef unsigned short bf16_t;
typedef __bf16 bf16x8 __attribute__((ext_vector_type(8)));
typedef float f32x4v __attribute__((ext_vector_type(4)));

__device__ __forceinline__ float bf2f(bf16_t u){
    return __uint_as_float(((unsigned int)u) << 16);
}
__device__ __forceinline__ bf16_t f2bf(float f){
    unsigned int x = __float_as_uint(f);
    return (bf16_t)((x + 0x7fffu + ((x >> 16) & 1u)) >> 16);
}
__device__ __forceinline__ unsigned pack2(float a, float b){
    return (unsigned)f2bf(a) | ((unsigned)f2bf(b) << 16);
}
__device__ __forceinline__ float gelu_exact(float x){
    return 0.5f * x * (1.0f + erff(x * 0.70710678118654752440f));
}
__device__ __forceinline__ float wave_reduce_sum(float v){
#pragma unroll
    for (int off = 32; off; off >>= 1) v += __shfl_xor(v, off);
    return v;
}

__global__ void zero_kernel(int* __restrict__ p, int n){
    int i = blockIdx.x * blockDim.x + threadIdx.x;
    if (i < n) p[i] = 0;
}

// ---- LN(atom_llm)*g+b -> bf16, concat onehot -> xln [NN][1088] ----
__global__ __launch_bounds__(256)
void ln_concat_kernel(const float* __restrict__ A, const float* __restrict__ onehot,
                      const float* __restrict__ g, const float* __restrict__ b,
                      bf16_t* __restrict__ xln){
    int wave = threadIdx.x >> 6, lane = threadIdx.x & 63;
    int row = (blockIdx.x << 2) + wave;
    const float* p = A + (size_t)row * DLLM;
    float4 v[4];
    float s = 0.f, sq = 0.f;
#pragma unroll
    for (int c = 0; c < 4; c++){
        v[c] = *(const float4*)(p + c * 256 + (lane << 2));
        s  += v[c].x + v[c].y + v[c].z + v[c].w;
        sq += v[c].x*v[c].x + v[c].y*v[c].y + v[c].z*v[c].z + v[c].w*v[c].w;
    }
    s = wave_reduce_sum(s); sq = wave_reduce_sum(sq);
    float mean = s * (1.0f / DLLM);
    float var  = sq * (1.0f / DLLM) - mean * mean;
    float rstd = rsqrtf(var + 1e-5f);
    bf16_t* out = xln + (size_t)row * 1088;
#pragma unroll
    for (int c = 0; c < 4; c++){
        float4 g4 = *(const float4*)(g + c * 256 + (lane << 2));
        float4 b4 = *(const float4*)(b + c * 256 + (lane << 2));
        float rx = (v[c].x - mean) * rstd * g4.x + b4.x;
        float ry = (v[c].y - mean) * rstd * g4.y + b4.y;
        float rz = (v[c].z - mean) * rstd * g4.z + b4.z;
        float rw = (v[c].w - mean) * rstd * g4.w + b4.w;
        ushort4 u; u.x = f2bf(rx); u.y = f2bf(ry); u.z = f2bf(rz); u.w = f2bf(rw);
        *(ushort4*)(out + c * 256 + (lane << 2)) = u;
    }
    out[1024 + lane] = f2bf(onehot[(size_t)row * COH + lane]);
}

// ---- eproj[l][t][:] = LN(edge_emb[t]) @ We[l] ----
__global__ __launch_bounds__(256)
void edgeproj_kernel(const float* __restrict__ edge_emb,
                     const float* __restrict__ lg, const float* __restrict__ lb,
                     const float* __restrict__ We, float* __restrict__ eproj){
    int l = blockIdx.x >> 3, t = blockIdx.x & 7;
    __shared__ float ea[EDIM];
    int tid = threadIdx.x;
    if (tid < 64){
        float v = edge_emb[t * EDIM + tid];
        float s = v, sq = v * v;
#pragma unroll
        for (int off = 32; off; off >>= 1){ s += __shfl_xor(s, off); sq += __shfl_xor(sq, off); }
        float mean = s * (1.f/64.f);
        float var  = sq * (1.f/64.f) - mean * mean;
        float rstd = rsqrtf(var + 1e-5f);
        ea[tid] = (v - mean) * rstd * lg[tid] + lb[tid];
    }
    __syncthreads();
    const float* W = We + (size_t)l * EDIM * DD;
    float s = 0.f;
#pragma unroll
    for (int k = 0; k < EDIM; k++) s += ea[k] * W[k * DD + tid];
    eproj[((l << 3) + t) * DD + tid] = s;
}

// ---- CSR build over dst (epack = srcLocal<<3 | etype) ----
__global__ void count_kernel(const int* __restrict__ dst, int* __restrict__ cnt){
    int e = blockIdx.x * blockDim.x + threadIdx.x;
    if (e < NE){
        int d = dst[e];
        if (d >= 0 && d < NN) atomicAdd(&cnt[d], 1);
    }
}

__global__ __launch_bounds__(1024)
void scan_kernel(const int* __restrict__ cnt, int* __restrict__ rowstart, int* __restrict__ cursor){
    __shared__ int sh[1024];
    int tid = threadIdx.x;
    int carry = 0;
    for (int base = 0; base < NN; base += 1024){
        int v = cnt[base + tid];
        sh[tid] = v; __syncthreads();
        for (int off = 1; off < 1024; off <<= 1){
            int t = (tid >= off) ? sh[tid - off] : 0;
            __syncthreads();
            sh[tid] += t;
            __syncthreads();
        }
        int excl = carry + sh[tid] - v;
        rowstart[base + tid] = excl;
        cursor[base + tid]   = excl;
        carry += sh[1023];
        __syncthreads();
    }
    if (tid == 0) rowstart[NN] = carry;
}

__global__ void scatter_kernel(const int* __restrict__ dst, const int* __restrict__ src,
                               const int* __restrict__ etype, int* __restrict__ cursor,
                               int* __restrict__ epack){
    int e = blockIdx.x * blockDim.x + threadIdx.x;
    if (e < NE){
        int d = dst[e];
        if (d >= 0 && d < NN){
            int p = atomicAdd(&cursor[d], 1);
            if (p >= 0 && p < NE){
                int sv = src[e]; if (sv < 0 || sv >= NN) sv = 0;
                epack[p] = ((sv & 127) << 3) | (etype[e] & 7);
            }
        }
    }
}

// ---- weight conversion / transposition to bf16 ----
__global__ void wcvt_in_kernel(const float* __restrict__ Wllm, const float* __restrict__ Woh,
                               bf16_t* __restrict__ dst){   // [256][1088]
    int idx = blockIdx.x * blockDim.x + threadIdx.x;
    if (idx >= 256 * 1088) return;
    int n = idx / 1088, k = idx % 1088;
    float v = (k < 1024) ? Wllm[(size_t)k * 256 + n] : Woh[(size_t)(k - 1024) * 256 + n];
    dst[idx] = f2bf(v);
}

__global__ void wcvt_qkvs_kernel(const float* __restrict__ Wq, const float* __restrict__ Wk,
                                 const float* __restrict__ Wv, const float* __restrict__ Ws,
                                 bf16_t* __restrict__ dst){  // [L][1024][256]
    int idx = blockIdx.x * blockDim.x + threadIdx.x;
    if (idx >= NLAYERS * 1024 * 256) return;
    int l = idx >> 18, rem = idx & 262143;
    int n = rem >> 8, k = rem & 255;
    int sel = n >> 8, nn = n & 255;
    const float* W = (sel == 0) ? Wq : (sel == 1) ? Wk : (sel == 2) ? Wv : Ws;
    dst[idx] = f2bf(W[(size_t)l * 65536 + (size_t)k * 256 + nn]);
}

__global__ void wcvt_w1_kernel(const float* __restrict__ W1, bf16_t* __restrict__ dst){ // [1024][256]
    int idx = blockIdx.x * blockDim.x + threadIdx.x;
    if (idx >= 1024 * 256) return;
    int n = idx >> 8, k = idx & 255;
    dst[idx] = f2bf(W1[(size_t)k * 1024 + n]);
}

__global__ void wcvt_w2_kernel(const float* __restrict__ W2, bf16_t* __restrict__ dst){ // [256][1024]
    int idx = blockIdx.x * blockDim.x + threadIdx.x;
    if (idx >= 256 * 1024) return;
    int n = idx >> 10, k = idx & 1023;
    dst[idx] = f2bf(W2[(size_t)k * 256 + n]);
}

__global__ void pack_bias_kernel(const float* __restrict__ bq, const float* __restrict__ bk,
                                 const float* __restrict__ bv, const float* __restrict__ bs,
                                 float* __restrict__ dst){   // [L][1024]
    int idx = blockIdx.x * blockDim.x + threadIdx.x;
    if (idx >= NLAYERS * 1024) return;
    int l = idx >> 10, n = idx & 1023;
    int sel = n >> 8, nn = n & 255;
    const float* B = (sel == 0) ? bq : (sel == 1) ? bk : (sel == 2) ? bv : bs;
    dst[idx] = B[l * 256 + nn];
}

// ---- bf16 MFMA GEMM: C = [epi](A @ BT^T [+bias]) ----
template<bool A_F32, bool HAS_BIAS, bool GELU_EP, bool MASK_EP, bool WRITE_F32, bool WRITE_BF16>
__global__ __launch_bounds__(256)
void mfma_gemm(const void* __restrict__ Av, const bf16_t* __restrict__ BT,
               float* __restrict__ Cf, bf16_t* __restrict__ Cb,
               int Ncols, int K,
               const float* __restrict__ bias, const float* __restrict__ mask)
{
    __shared__ bf16_t As[128][40];
    __shared__ bf16_t Bs[128][40];
    const int tid  = threadIdx.x;
    const int rowBase = blockIdx.y << 7;
    const int colBase = blockIdx.x << 7;
    const int lane = tid & 63;
    const int wave = tid >> 6;
    const int wm = wave >> 1, wn = wave & 1;
    const int lhi = lane >> 4, llo = lane & 15;
    const int r0 = tid >> 2;
    const int q0 = (tid & 3) << 3;

    f32x4v acc[4][4];
#pragma unroll
    for (int m = 0; m < 4; m++)
#pragma unroll
        for (int n = 0; n < 4; n++)
            acc[m][n] = (f32x4v){0.f, 0.f, 0.f, 0.f};

    const int nk = K >> 5;
    for (int ks = 0; ks < nk; ks++){
        const int k0 = ks << 5;
        if constexpr (A_F32){
            const float* Ap = (const float*)Av;
#pragma unroll
            for (int half = 0; half < 2; half++){
                int r = r0 + half * 64;
                const float* p = Ap + (size_t)(rowBase + r) * K + (k0 + q0);
                float4 a = *(const float4*)p;
                float4 b = *(const float4*)(p + 4);
                uint4 pk;
                pk.x = pack2(a.x, a.y); pk.y = pack2(a.z, a.w);
                pk.z = pack2(b.x, b.y); pk.w = pack2(b.z, b.w);
                *(uint4*)&As[r][q0] = pk;
            }
        } else {
            const bf16_t* Ap = (const bf16_t*)Av;
#pragma unroll
            for (int half = 0; half < 2; half++){
                int r = r0 + half * 64;
                *(uint4*)&As[r][q0] = *(const uint4*)(Ap + (size_t)(rowBase + r) * K + (k0 + q0));
            }
        }
#pragma unroll
        for (int half = 0; half < 2; half++){
            int r = r0 + half * 64;
            *(uint4*)&Bs[r][q0] = *(const uint4*)(BT + (size_t)(colBase + r) * K + (k0 + q0));
        }
        __syncthreads();
        bf16x8 af[4], bfr[4];
#pragma unroll
        for (int m = 0; m < 4; m++)
            af[m] = *(const bf16x8*)&As[(wm << 6) + (m << 4) + llo][lhi << 3];
#pragma unroll
        for (int n = 0; n < 4; n++)
            bfr[n] = *(const bf16x8*)&Bs[(wn << 6) + (n << 4) + llo][lhi << 3];
#pragma unroll
        for (int m = 0; m < 4; m++)
#pragma unroll
            for (int n = 0; n < 4; n++)
                acc[m][n] = __builtin_amdgcn_mfma_f32_16x16x32_bf16(af[m], bfr[n], acc[m][n], 0, 0, 0);
        __syncthreads();
    }

#pragma unroll
    for (int m = 0; m < 4; m++){
        const int rowb = rowBase + (wm << 6) + (m << 4) + (lhi << 2);
#pragma unroll
        for (int n = 0; n < 4; n++){
            const int col = colBase + (wn << 6) + (n << 4) + llo;
            float bv = 0.f;
            if constexpr (HAS_BIAS) bv = bias[col];
#pragma unroll
            for (int r = 0; r < 4; r++){
                float v = acc[m][n][r] + bv;
                if constexpr (GELU_EP) v = gelu_exact(v);
                if constexpr (MASK_EP) v *= mask[rowb + r];
                if constexpr (WRITE_F32) Cf[(size_t)(rowb + r) * Ncols + col] = v;
                if constexpr (WRITE_BF16) Cb[(size_t)(rowb + r) * Ncols + col] = f2bf(v);
            }
        }
    }
}

// ---- fused per-graph attention + beta gate + GraphNorm + GELU ----
// block = one graph (128 nodes), 1024 threads = 16 waves, wave owns 8 dst nodes.
// lane l owns dims 4l..4l+3. No K/V LDS staging (L2-resident, coalesced row reads).
// h updated in place: h = gelu(graphnorm(h + beta*xr + (1-beta)*attn_out)).
__global__ __launch_bounds__(1024)
void attn_gnorm_kernel(const bf16_t* __restrict__ QKVS, float* __restrict__ h,
                       const int* __restrict__ rowstart, const int* __restrict__ epack,
                       const float* __restrict__ eproj, const float* __restrict__ Wb,
                       const float* __restrict__ gw, const float* __restrict__ gb,
                       const float* __restrict__ gms)
{
    __shared__ float epl[8][256];       // 8 KB
    __shared__ float gsumL[16][256];    // 16 KB
    __shared__ float gsqL[16][256];     // 16 KB
    __shared__ float msubL[256], rswL[256], gbL[256];  // 3 KB
    const int g = blockIdx.x;
    const int tid = threadIdx.x;
    const int wave = tid >> 6, lane = tid & 63;
    const int d4 = lane << 2;
    const size_t gbase = (size_t)g << 17;   // g * 128 * 1024

    for (int i = tid; i < 2048; i += 1024) epl[i >> 8][i & 255] = eproj[i];
    __syncthreads();

    float4 w0 = *(const float4*)(Wb + d4);
    float4 w1 = *(const float4*)(Wb + 256 + d4);
    float4 w2 = *(const float4*)(Wb + 512 + d4);

    float Sreg[8][4];
    float gs0 = 0.f, gs1 = 0.f, gs2 = 0.f, gs3 = 0.f;
    float gq0 = 0.f, gq1 = 0.f, gq2 = 0.f, gq3 = 0.f;

#pragma unroll
    for (int ni = 0; ni < 8; ni++){
        const int nl = (wave << 3) + ni;
        const int node = (g << 7) + nl;
        int s0 = rowstart[node];
        int deg = rowstart[node + 1] - s0;
        if (deg < 0) deg = 0;
        ushort4 qu = *(const ushort4*)(QKVS + gbase + ((size_t)nl << 10) + d4);
        float q0 = bf2f(qu.x), q1 = bf2f(qu.y), q2 = bf2f(qu.z), q3 = bf2f(qu.w);
        float m = -1e30f, den = 0.f;
        float v0 = 0.f, v1 = 0.f, v2 = 0.f, v3 = 0.f;
        for (int c0 = 0; c0 < deg; c0 += 8){
            int ce = deg - c0; if (ce > 8) ce = 8;   // wave-uniform
            int pk[8]; float pa[8];
#pragma unroll
            for (int i = 0; i < 8; i++)
                pk[i] = (i < ce) ? epack[s0 + c0 + i] : 0;
#pragma unroll
            for (int i = 0; i < 8; i++){
                if (i < ce){
                    int sl = pk[i] >> 3, t = pk[i] & 7;
                    ushort4 ku = *(const ushort4*)(QKVS + gbase + ((size_t)sl << 10) + 256 + d4);
                    float4 ev = *(const float4*)&epl[t][d4];
                    float d = q0 * (bf2f(ku.x) + ev.x) + q1 * (bf2f(ku.y) + ev.y)
                            + q2 * (bf2f(ku.z) + ev.z) + q3 * (bf2f(ku.w) + ev.w);
                    d += __shfl_xor(d, 1); d += __shfl_xor(d, 2);
                    d += __shfl_xor(d, 4); d += __shfl_xor(d, 8);
                    pa[i] = d * 0.125f;   // 1/sqrt(64)
                } else {
                    pa[i] = -1e30f;
                }
            }
            float cm = pa[0];
#pragma unroll
            for (int i = 1; i < 8; i++) cm = fmaxf(cm, pa[i]);
            float mnew = fmaxf(m, cm);
            float scale = expf(m - mnew);
            den *= scale; v0 *= scale; v1 *= scale; v2 *= scale; v3 *= scale;
#pragma unroll
            for (int i = 0; i < 8; i++){
                if (i < ce){
                    int sl = pk[i] >> 3, t = pk[i] & 7;
                    float w = expf(pa[i] - mnew);
                    den += w;
                    ushort4 vu = *(const ushort4*)(QKVS + gbase + ((size_t)sl << 10) + 512 + d4);
                    float4 ev = *(const float4*)&epl[t][d4];
                    v0 = fmaf(w, bf2f(vu.x) + ev.x, v0);
                    v1 = fmaf(w, bf2f(vu.y) + ev.y, v1);
                    v2 = fmaf(w, bf2f(vu.z) + ev.z, v2);
                    v3 = fmaf(w, bf2f(vu.w) + ev.w, v3);
                }
            }
            m = mnew;
        }
        float inv = (den > 0.f) ? 1.f / den : 0.f;
        v0 *= inv; v1 *= inv; v2 *= inv; v3 *= inv;
        ushort4 xu = *(const ushort4*)(QKVS + gbase + ((size_t)nl << 10) + 768 + d4);
        float x0 = bf2f(xu.x), x1 = bf2f(xu.y), x2 = bf2f(xu.z), x3 = bf2f(xu.w);
        float part = v0*w0.x + v1*w0.y + v2*w0.z + v3*w0.w
                   + x0*w1.x + x1*w1.y + x2*w1.z + x3*w1.w
                   + (v0-x0)*w2.x + (v1-x1)*w2.y + (v2-x2)*w2.z + (v3-x3)*w2.w;
        part = wave_reduce_sum(part);
        float beta = 1.f / (1.f + expf(-part));
        float4 hv = *(const float4*)(h + ((size_t)node << 8) + d4);
        float r0v = hv.x + beta * x0 + (1.f - beta) * v0;
        float r1v = hv.y + beta * x1 + (1.f - beta) * v1;
        float r2v = hv.z + beta * x2 + (1.f - beta) * v2;
        float r3v = hv.w + beta * x3 + (1.f - beta) * v3;
        Sreg[ni][0] = r0v; Sreg[ni][1] = r1v; Sreg[ni][2] = r2v; Sreg[ni][3] = r3v;
        gs0 += r0v; gs1 += r1v; gs2 += r2v; gs3 += r3v;
        gq0 = fmaf(r0v, r0v, gq0); gq1 = fmaf(r1v, r1v, gq1);
        gq2 = fmaf(r2v, r2v, gq2); gq3 = fmaf(r3v, r3v, gq3);
    }

    *(float4*)&gsumL[wave][d4] = make_float4(gs0, gs1, gs2, gs3);
    *(float4*)&gsqL[wave][d4]  = make_float4(gq0, gq1, gq2, gq3);
    __syncthreads();
    if (tid < 256){
        float s = 0.f, sq = 0.f;
#pragma unroll
        for (int j = 0; j < 16; j++){ s += gsumL[j][tid]; sq += gsqL[j][tid]; }
        float mean = s * (1.f / 128.f);
        float msub = mean * gms[tid];
        // var = E[(x-msub)^2] = E[x^2] - 2*msub*E[x] + msub^2 (uncentered, per reference)
        float var = sq * (1.f / 128.f) - 2.f * msub * mean + msub * msub;
        float rs = rsqrtf(var + 1e-5f);
        msubL[tid] = msub;
        rswL[tid]  = rs * gw[tid];
        gbL[tid]   = gb[tid];
    }
    __syncthreads();
    float4 ms4 = *(const float4*)&msubL[d4];
    float4 rw4 = *(const float4*)&rswL[d4];
    float4 gb4 = *(const float4*)&gbL[d4];
#pragma unroll
    for (int ni = 0; ni < 8; ni++){
        const int node = (g << 7) + (wave << 3) + ni;
        float4 r;
        r.x = gelu_exact((Sreg[ni][0] - ms4.x) * rw4.x + gb4.x);
        r.y = gelu_exact((Sreg[ni][1] - ms4.y) * rw4.y + gb4.y);
        r.z = gelu_exact((Sreg[ni][2] - ms4.z) * rw4.z + gb4.z);
        r.w = gelu_exact((Sreg[ni][3] - ms4.w) * rw4.w + gb4.w);
        *(float4*)(h + ((size_t)node << 8) + d4) = r;
    }
}

// ---- final: out = LN(h + ff) * mask ----
__global__ __launch_bounds__(256)
void final_ln_kernel(const float* __restrict__ h, const float* __restrict__ ff,
                     const float* __restrict__ g, const float* __restrict__ b,
                     const float* __restrict__ mask, float* __restrict__ outp)
{
    int wave = threadIdx.x >> 6, lane = threadIdx.x & 63;
    int node = (blockIdx.x << 2) + wave;
    int d0 = lane << 2;
    float4 hv = *(const float4*)(h  + (size_t)node * DD + d0);
    float4 fv = *(const float4*)(ff + (size_t)node * DD + d0);
    float4 v; v.x = hv.x + fv.x; v.y = hv.y + fv.y; v.z = hv.z + fv.z; v.w = hv.w + fv.w;
    float s  = v.x + v.y + v.z + v.w;
    float sq = v.x*v.x + v.y*v.y + v.z*v.z + v.w*v.w;
    s = wave_reduce_sum(s); sq = wave_reduce_sum(sq);
    float mean = s * (1.f / DD);
    float var  = sq * (1.f / DD) - mean * mean;
    float rs = rsqrtf(var + 1e-5f);
    float mk = mask[node];
    float4 g4 = *(const float4*)(g + d0), b4 = *(const float4*)(b + d0);
    float4 r;
    r.x = ((v.x - mean) * rs * g4.x + b4.x) * mk;
    r.y = ((v.y - mean) * rs * g4.y + b4.y) * mk;
    r.z = ((v.z - mean) * rs * g4.z + b4.z) * mk;
    r.w = ((v.w - mean) * rs * g4.w + b4.w) * mk;
    *(float4*)(outp + (size_t)node * DD + d0) = r;
}

extern "C" void kernel_launch(void* const* d_in, const int* in_sizes, int n_in,
                              void* d_out, int out_size, void* d_ws, size_t ws_size,
                              hipStream_t stream)
{
    if (n_in < 33) return;
    if (in_sizes[0] != NN * DLLM) return;
    if (in_sizes[3] != 2 * NE) return;
    if (in_sizes[8] != DLLM * DD) return;
    if (in_sizes[27] != DD * 4 * DD) return;
    if (out_size != NN * DD) return;

    const float* atom_llm    = (const float*)d_in[0];
    const float* atom_onehot = (const float*)d_in[1];
    const float* mask        = (const float*)d_in[2];
    const int*   edge_index  = (const int*)d_in[3];
    const int*   etype       = (const int*)d_in[4];
    const float* ln_llm_g    = (const float*)d_in[6];
    const float* ln_llm_b    = (const float*)d_in[7];
    const float* W_llm       = (const float*)d_in[8];
    const float* b_llm       = (const float*)d_in[9];
    const float* W_oh        = (const float*)d_in[10];
    const float* edge_emb    = (const float*)d_in[11];
    const float* edge_ln_g   = (const float*)d_in[12];
    const float* edge_ln_b   = (const float*)d_in[13];
    const float* Wq          = (const float*)d_in[14];
    const float* bq          = (const float*)d_in[15];
    const float* Wk          = (const float*)d_in[16];
    const float* bk          = (const float*)d_in[17];
    const float* Wv          = (const float*)d_in[18];
    const float* bv          = (const float*)d_in[19];
    const float* We          = (const float*)d_in[20];
    const float* Ws          = (const float*)d_in[21];
    const float* bs          = (const float*)d_in[22];
    const float* Wb          = (const float*)d_in[23];
    const float* gn_w        = (const float*)d_in[24];
    const float* gn_b        = (const float*)d_in[25];
    const float* gn_ms       = (const float*)d_in[26];
    const float* W1          = (const float*)d_in[27];
    const float* b1          = (const float*)d_in[28];
    const float* W2          = (const float*)d_in[29];
    const float* b2          = (const float*)d_in[30];
    const float* out_ln_g    = (const float*)d_in[31];
    const float* out_ln_b    = (const float*)d_in[32];

    const int* srcv = edge_index;
    const int* dstv = edge_index + NE;

    char* ws = (char*)d_ws;
    size_t off = 0;
    auto alloc = [&](size_t bytes) -> char* {
        char* p = ws + off; off += (bytes + 255) / 256 * 256; return p;
    };
    float*  h    = (float*)alloc((size_t)NN * DD * sizeof(float));      // 33.5 MB
    bf16_t* reg3 = (bf16_t*)alloc((size_t)NN * 1088 * sizeof(bf16_t));  // 71.3 MB: xln / qkvs / t1
    bf16_t* wt_in   = (bf16_t*)alloc((size_t)256 * 1088 * sizeof(bf16_t));
    bf16_t* wt_qkvs = (bf16_t*)alloc((size_t)NLAYERS * 1024 * 256 * sizeof(bf16_t));
    bf16_t* wt_w1   = (bf16_t*)alloc((size_t)1024 * 256 * sizeof(bf16_t));
    bf16_t* wt_w2   = (bf16_t*)alloc((size_t)256 * 1024 * sizeof(bf16_t));
    float*  biasp   = (float*)alloc((size_t)NLAYERS * 1024 * sizeof(float));
    float*  eproj   = (float*)alloc((size_t)NLAYERS * NETT * DD * sizeof(float));
    int* cnt      = (int*)alloc((size_t)NN * sizeof(int));
    int* rowstart = (int*)alloc((size_t)(NN + 1) * sizeof(int));
    int* cursor   = (int*)alloc((size_t)NN * sizeof(int));
    int* epack    = (int*)alloc((size_t)NE * sizeof(int));
    bf16_t* xln  = reg3;      // [NN][1088]
    bf16_t* qkvs = reg3;      // [NN][1024]
    bf16_t* t1   = reg3;      // [NN][1024]
    float*  S    = (float*)d_out;  // FFN t2 scratch only

    if (ws_size < off) return;

    // CSR build
    zero_kernel<<<NN / 256, 256, 0, stream>>>(cnt, NN);
    count_kernel<<<NE / 256, 256, 0, stream>>>(dstv, cnt);
    scan_kernel<<<1, 1024, 0, stream>>>(cnt, rowstart, cursor);
    scatter_kernel<<<NE / 256, 256, 0, stream>>>(dstv, srcv, etype, cursor, epack);

    // precompute
    ln_concat_kernel<<<NN / 4, 256, 0, stream>>>(atom_llm, atom_onehot, ln_llm_g, ln_llm_b, xln);
    edgeproj_kernel<<<NLAYERS * NETT, 256, 0, stream>>>(edge_emb, edge_ln_g, edge_ln_b, We, eproj);
    wcvt_in_kernel<<<(256 * 1088 + 255) / 256, 256, 0, stream>>>(W_llm, W_oh, wt_in);
    wcvt_qkvs_kernel<<<(NLAYERS * 1024 * 256) / 256, 256, 0, stream>>>(Wq, Wk, Wv, Ws, wt_qkvs);
    wcvt_w1_kernel<<<(1024 * 256) / 256, 256, 0, stream>>>(W1, wt_w1);
    wcvt_w2_kernel<<<(256 * 1024) / 256, 256, 0, stream>>>(W2, wt_w2);
    pack_bias_kernel<<<(NLAYERS * 1024) / 256, 256, 0, stream>>>(bq, bk, bv, bs, biasp);

    // input proj: h = (xln @ [W_llm;W_oh] + b_llm) * mask   [f32]
    {
        dim3 grid(DD / 128, NN / 128);
        mfma_gemm<false, true, false, true, true, false><<<grid, 256, 0, stream>>>(
            xln, wt_in, h, nullptr, DD, 1088, b_llm, mask);
    }

    for (int l = 0; l < NLAYERS; l++){
        dim3 grid(1024 / 128, NN / 128);
        mfma_gemm<true, true, false, false, false, true><<<grid, 256, 0, stream>>>(
            h, wt_qkvs + (size_t)l * 1024 * 256, nullptr, qkvs, 1024, DD,
            biasp + (size_t)l * 1024, nullptr);

        attn_gnorm_kernel<<<NB, 1024, 0, stream>>>(qkvs, h, rowstart, epack,
                                                   eproj + (size_t)l * NETT * DD,
                                                   Wb + (size_t)l * 768,
                                                   gn_w + l * DD, gn_b + l * DD, gn_ms + l * DD);
    }

    // FFN: t1 = gelu(h @ W1 + b1) [bf16]; S = t1 @ W2 + b2 [f32]; out = LN(h + S) * mask
    {
        dim3 grid1(1024 / 128, NN / 128);
        mfma_gemm<true, true, true, false, false, true><<<grid1, 256, 0, stream>>>(
            h, wt_w1, nullptr, t1, 1024, DD, b1, nullptr);
        dim3 grid2(DD / 128, NN / 128);
        mfma_gemm<false, true, false, false, true, false><<<grid2, 256, 0, stream>>>(
            t1, wt_w2, S, nullptr, DD, 1024, b2, nullptr);
        final_ln_kernel<<<NN / 4, 256, 0, stream>>>(h, S, out_ln_g, out_ln_b, mask,
                                                    (float*)d_out);
    }
}